// Round 11
// baseline (469.508 us; speedup 1.0000x reference)
//
#include <hip/hip_runtime.h>
#include <hip/hip_bf16.h>
#include <hip/hip_fp16.h>
#include <math.h>

#define NN 20000
#define EE 320000
#define GG 64
#define CH 32   // attention chunk size (edges)

typedef __hip_bfloat16 bf16;
typedef __attribute__((ext_vector_type(8))) short short8;
typedef __attribute__((ext_vector_type(4))) float f32x4;
typedef __attribute__((ext_vector_type(4))) unsigned int uint4v;
typedef __attribute__((ext_vector_type(2))) _Float16 half2v;
typedef unsigned int uint;
typedef unsigned short ushort;

__device__ __forceinline__ float bfr2f(ushort u) {
    union { uint i; float f; } c; c.i = ((uint)u) << 16; return c.f;
}
__device__ __forceinline__ ushort f2bfr(float f) {
    bf16 h = __float2bfloat16(f);
    return *(ushort*)&h;
}

// fp16-pair dot with f32 accumulate: c + a.x*b.x + a.y*b.y
__device__ __forceinline__ float dot2acc(uint a, uint b, float c) {
#if __has_builtin(__builtin_amdgcn_fdot2)
    return __builtin_amdgcn_fdot2(__builtin_bit_cast(half2v, a),
                                  __builtin_bit_cast(half2v, b), c, false);
#else
    half2v ha = __builtin_bit_cast(half2v, a);
    half2v hb = __builtin_bit_cast(half2v, b);
    return c + (float)ha.x * (float)hb.x + (float)ha.y * (float)hb.y;
#endif
}

// ---------------------------------------------------------------------------
// async global->LDS 16B copy
// ---------------------------------------------------------------------------
__device__ __forceinline__ void load_lds16(const void* g, void* l) {
    __builtin_amdgcn_global_load_lds(
        (const __attribute__((address_space(1))) unsigned int*)g,
        (__attribute__((address_space(3))) unsigned int*)l, 16, 0, 0);
}

// ---------------------------------------------------------------------------
// fused prep: x->bf16 (strided), LDS-tiled weight transposes, biases, count
// ---------------------------------------------------------------------------
#define PREP_CONV  10000                 // NN*128/256 blocks: x convert
#define PREP_TP    (PREP_CONV + 800)     // 800 32x32 transpose tiles
#define PREP_BIAS  (PREP_TP + 8)
#define PREP_COUNT (PREP_BIAS + 1250)

__global__ __launch_bounds__(256) void prep_kernel(
    const float* x, bf16* xm1,
    const float* s1_wr, const float* s1_wl, const float* s2_wr, const float* s2_wl,
    const float* t1_wq, const float* t1_wk, const float* t1_wv, const float* t1_ws,
    const float* t2_wq, const float* t2_wk, const float* t2_wv, const float* t2_ws,
    const float* p1_w, const float* p2_w,
    bf16* w1cat, bf16* w2cat, bf16* qw1, bf16* qw2, bf16* p1t, bf16* p2t,
    const float* b1q, const float* b1k, const float* b1v, const float* b1s,
    const float* b2q, const float* b2k, const float* b2v, const float* b2s,
    float* qb1, float* qb2,
    const int* dst, int* cnt) {
    __shared__ float tile[32][33];
    int bid = blockIdx.x;
    int tid = threadIdx.x;
    if (bid < PREP_CONV) {
        int i = bid * 256 + tid;  // < NN*128
        int r = i >> 7, c = i & 127;
        xm1[(size_t)r * 256 + c] = __float2bfloat16(x[i]);
    } else if (bid < PREP_TP) {
        // ---- LDS-tiled transpose: Wt[n][KOFF+k] = bf16(W[k][n]) ----
        int tb = bid - PREP_CONV;   // 0..799
        const float* W; bf16* Wt; int KW, NW, KT, KO, lt;
        const float* t1w[4] = {t1_wq, t1_wk, t1_wv, t1_ws};
        const float* t2w[4] = {t2_wq, t2_wk, t2_wv, t2_ws};
        if (tb < 16)       { W = s1_wr; Wt = w1cat; KW = 128; NW = 128; KT = 256; KO = 0;   lt = tb; }
        else if (tb < 32)  { W = s1_wl; Wt = w1cat; KW = 128; NW = 128; KT = 256; KO = 128; lt = tb - 16; }
        else if (tb < 64)  { W = s2_wr; Wt = w2cat; KW = 128; NW = 256; KT = 256; KO = 0;   lt = tb - 32; }
        else if (tb < 96)  { W = s2_wl; Wt = w2cat; KW = 128; NW = 256; KT = 256; KO = 128; lt = tb - 64; }
        else if (tb < 352) { int m = (tb - 96) >> 6;  W = t1w[m]; Wt = qw1 + m * 65536; KW = 256; NW = 256; KT = 256; KO = 0; lt = (tb - 96) & 63; }
        else if (tb < 608) { int m = (tb - 352) >> 6; W = t2w[m]; Wt = qw2 + m * 65536; KW = 256; NW = 256; KT = 256; KO = 0; lt = (tb - 352) & 63; }
        else if (tb < 736) { W = p1_w; Wt = p1t; KW = 256; NW = 512; KT = 256; KO = 0; lt = tb - 608; }
        else               { W = p2_w; Wt = p2t; KW = 512; NW = 128; KT = 512; KO = 0; lt = tb - 736; }
        int ntiles_n = NW >> 5;
        int k0 = (lt / ntiles_n) * 32;
        int n0 = (lt % ntiles_n) * 32;
        int tx = tid & 31, ty = tid >> 5;   // ty 0..7
        #pragma unroll
        for (int r = 0; r < 4; r++)
            tile[ty + 8 * r][tx] = W[(size_t)(k0 + ty + 8 * r) * NW + n0 + tx];
        __syncthreads();
        #pragma unroll
        for (int r = 0; r < 4; r++)
            Wt[(size_t)(n0 + ty + 8 * r) * KT + KO + k0 + tx] =
                __float2bfloat16(tile[tx][ty + 8 * r]);
    } else if (bid < PREP_BIAS) {
        int i = (bid - PREP_TP) * 256 + tid;
        if (i < 2048) {
            float* d = (i < 1024) ? qb1 : qb2;
            int j = i & 1023;
            const float* s;
            if (i < 1024) s = (j < 256) ? b1q : (j < 512) ? b1k : (j < 768) ? b1v : b1s;
            else          s = (j < 256) ? b2q : (j < 512) ? b2k : (j < 768) ? b2v : b2s;
            d[j] = s[j & 255];
        }
    } else {
        int e = (bid - PREP_BIAS) * 256 + tid;
        if (e < EE) atomicAdd(&cnt[dst[e]], 1);
    }
}

// ---------------------------------------------------------------------------
// scan: shfl-based wave scan. cnt -> off (excl), cursor.
// ---------------------------------------------------------------------------
__global__ __launch_bounds__(1024) void scan_kernel(int* __restrict__ cnt,
                                                    int* __restrict__ off, int n) {
    __shared__ int wsum[16];
    __shared__ int carry_s;
    int tid = threadIdx.x;
    int lane = tid & 63, wid = tid >> 6;
    if (tid == 0) { carry_s = 0; off[0] = 0; }
    __syncthreads();
    for (int base = 0; base < n; base += 1024) {
        int idx = base + tid;
        int val = (idx < n) ? cnt[idx] : 0;
        int x = val;
        #pragma unroll
        for (int s = 1; s < 64; s <<= 1) {
            int y = __shfl_up(x, s, 64);
            if (lane >= s) x += y;
        }
        if (lane == 63) wsum[wid] = x;
        __syncthreads();
        if (tid == 0) {
            int c = carry_s;
            #pragma unroll
            for (int w = 0; w < 16; w++) { int t = wsum[w]; wsum[w] = c; c += t; }
            carry_s = c;
        }
        __syncthreads();
        int incl = wsum[wid] + x;
        if (idx < n) {
            off[idx + 1] = incl;
            cnt[idx] = incl - val;
        }
        __syncthreads();
    }
}

__global__ __launch_bounds__(256) void fill_kernel(const int* __restrict__ src,
                                                   const int* __restrict__ dst,
                                                   int* __restrict__ cursor,
                                                   int* __restrict__ csr_src, int E) {
    int e = blockIdx.x * 256 + threadIdx.x;
    if (e < E) {
        int p = atomicAdd(&cursor[dst[e]], 1);
        csr_src[p] = src[e];
    }
}

// ---------------------------------------------------------------------------
// Mean aggregation: 4 nodes/block, 1 wave/node, bf16x2/lane, unroll x8.
// ---------------------------------------------------------------------------
__global__ __launch_bounds__(256) void mean2_kernel(const bf16* __restrict__ x, int xstride,
                                                    const int* __restrict__ off,
                                                    const int* __restrict__ csr_src,
                                                    bf16* __restrict__ outp, int ostride) {
    int node = blockIdx.x * 4 + (threadIdx.x >> 6);
    int lane = threadIdx.x & 63;
    int e0 = off[node], e1 = off[node + 1];
    float s0 = 0.f, s1 = 0.f;
    int e = e0;
    for (; e + 7 < e1; e += 8) {
        uint a[8];
        #pragma unroll
        for (int j = 0; j < 8; j++) {
            int sa = csr_src[e + j];
            a[j] = *(const uint*)(x + (size_t)sa * xstride + lane * 2);
        }
        #pragma unroll
        for (int j = 0; j < 8; j++) {
            union { uint i; float f; } t;
            t.i = a[j] << 16; s0 += t.f;
            t.i = a[j] & 0xffff0000u; s1 += t.f;
        }
    }
    for (; e < e1; e++) {
        int sa = csr_src[e];
        uint a = *(const uint*)(x + (size_t)sa * xstride + lane * 2);
        union { uint i; float f; } t;
        t.i = a << 16; s0 += t.f; t.i = a & 0xffff0000u; s1 += t.f;
    }
    int deg = e1 - e0;
    float inv = (deg > 0) ? 1.f / (float)deg : 0.f;
    uint r = ((uint)f2bfr(s1 * inv) << 16) | (uint)f2bfr(s0 * inv);
    *(uint*)(outp + (size_t)node * ostride + lane * 2) = r;
}

// ---------------------------------------------------------------------------
// bf16 MFMA GEMM: C[M,N] = A[M,K] @ Wt[N,K]^T, fused epilogue. BK=64.
// MODE 2: relu(+bias), bf16.
// MODE 5: +bias; store f16 for gn<512 (q,k), bf16 else (v,skip)  [qkvs]
// MODE 4: sigmoid(+bias) then grouped max-pool (sorted batch) -> ~1 atomic/col.
// ---------------------------------------------------------------------------
template <int MODE, int TM>
__global__ __launch_bounds__(256, (TM == 128) ? 3 : 4)
void gemm_kernel(const bf16* __restrict__ A,
                 const bf16* __restrict__ Wt,
                 const float* __restrict__ bias,
                 void* __restrict__ Cv,
                 int M, int K, int N, int cstride,
                 const int* __restrict__ batch,
                 float* __restrict__ pool_out) {
    constexpr int NT = (TM == 128) ? 4 : 2;   // n-tiles per wave
    __shared__ short As[TM * 64];
    __shared__ short Bs[128 * 64];
    __shared__ int bat[TM];
    int t = threadIdx.x;
    int lane = t & 63;
    int wave = t >> 6;
    int wm = (TM == 128) ? (wave >> 1) * 64 : 0;
    int wn = (TM == 128) ? (wave & 1) * 64 : wave * 32;
    int bm = blockIdx.y * TM, bn = blockIdx.x * 128;
    int quad = lane >> 4, l16 = lane & 15;
    int srow = t >> 3;           // 32 staging rows per round
    int scol = (t & 7) * 8;      // 64 cols in 8x 16B chunks

    if (MODE == 4 && t < TM) bat[t] = batch[min(bm + t, M - 1)];

    f32x4 acc[4][NT];
    f32x4 zero = {0.f, 0.f, 0.f, 0.f};
    #pragma unroll
    for (int i = 0; i < 4; i++)
        #pragma unroll
        for (int j = 0; j < NT; j++) acc[i][j] = zero;

    for (int kk = 0; kk < K; kk += 64) {
        #pragma unroll
        for (int r = 0; r < TM / 32; r++) {
            int row = r * 32 + srow;
            int gm = bm + row; gm = (gm < M) ? gm : (M - 1);
            load_lds16(A + (size_t)gm * K + kk + scol, &As[row * 64 + scol]);
        }
        #pragma unroll
        for (int r = 0; r < 4; r++) {
            int row = r * 32 + srow;
            load_lds16(Wt + (size_t)(bn + row) * K + kk + scol, &Bs[row * 64 + scol]);
        }
        __syncthreads();
        #pragma unroll
        for (int ks = 0; ks < 2; ks++) {
            short8 af[4], bfr[NT];
            #pragma unroll
            for (int i = 0; i < 4; i++)
                af[i] = *(const short8*)&As[(wm + i * 16 + l16) * 64 + ks * 32 + quad * 8];
            #pragma unroll
            for (int j = 0; j < NT; j++)
                bfr[j] = *(const short8*)&Bs[(wn + j * 16 + l16) * 64 + ks * 32 + quad * 8];
            #pragma unroll
            for (int i = 0; i < 4; i++)
                #pragma unroll
                for (int j = 0; j < NT; j++)
                    acc[i][j] = __builtin_amdgcn_mfma_f32_16x16x32_bf16(af[i], bfr[j], acc[i][j], 0, 0, 0);
        }
        __syncthreads();
    }

    if (MODE == 4) {
        int g0 = bat[0], gL = bat[TM - 1];
        #pragma unroll
        for (int j = 0; j < NT; j++) {
            int gn = bn + wn + j * 16 + l16;
            float m0 = 0.f, m1 = 0.f;
            #pragma unroll
            for (int i = 0; i < 4; i++) {
                #pragma unroll
                for (int r = 0; r < 4; r++) {
                    int row = i * 16 + quad * 4 + r;
                    int gm = bm + row;
                    if (gm >= M) continue;
                    float v = acc[i][j][r] + bias[gn];
                    v = 1.f / (1.f + expf(-v));
                    int g = bat[row];
                    if (g == g0) m0 = fmaxf(m0, v);
                    else if (g == gL) m1 = fmaxf(m1, v);
                    else atomicMax((int*)&pool_out[g * 128 + gn], __float_as_int(v));
                }
            }
            m0 = fmaxf(m0, __shfl_xor(m0, 16));
            m0 = fmaxf(m0, __shfl_xor(m0, 32));
            m1 = fmaxf(m1, __shfl_xor(m1, 16));
            m1 = fmaxf(m1, __shfl_xor(m1, 32));
            if (quad == 0) {
                atomicMax((int*)&pool_out[g0 * 128 + gn], __float_as_int(m0));
                if (gL != g0)
                    atomicMax((int*)&pool_out[gL * 128 + gn], __float_as_int(m1));
            }
        }
        return;
    }

    // epilogue: C/D layout col=lane&15, row=quad*4+reg
    #pragma unroll
    for (int i = 0; i < 4; i++) {
        int gm0 = bm + wm + i * 16 + quad * 4;
        #pragma unroll
        for (int j = 0; j < NT; j++) {
            int gn = bn + wn + j * 16 + l16;
            #pragma unroll
            for (int r = 0; r < 4; r++) {
                int gm = gm0 + r;
                if (gm >= M) continue;
                float v = acc[i][j][r] + bias[gn];
                if (MODE == 2) v = fmaxf(v, 0.f);
                ushort st;
                if (MODE == 5 && gn < 512) {
                    __half hh = __float2half(v);
                    st = *(ushort*)&hh;
                } else {
                    st = f2bfr(v);
                }
                ((ushort*)Cv)[(size_t)gm * cstride + gn] = st;
            }
        }
    }
}

template <int MODE, int TM>
static void launch_gemm(const bf16* A, const bf16* Wt, const float* bias, void* C,
                        int M, int K, int N, int cstride, hipStream_t st,
                        const int* batch = nullptr, float* pool_out = nullptr) {
    dim3 grid(N / 128, (M + TM - 1) / TM);
    hipLaunchKernelGGL((gemm_kernel<MODE, TM>), grid, dim3(256), 0, st,
                       A, Wt, bias, C, M, K, N, cstride, batch, pool_out);
}

// ---------------------------------------------------------------------------
// TransformerConv attention v7: CH=32, thread-per-(edge,head) dot.
// qkvs row stride 1024: [q f16(256) k f16(256) v bf16(256) skip bf16(256)].
// Phase A: 256 threads = 32 edges x 8 heads; each thread does the FULL
// 32-dim head dot (16 fdot2, no shuffle) and writes p = exp directly.
// Phase C: (head hc, dimpair dp, edge-parity epar): 16 uint v loads cover
// 32 edges x 2 dims; pair-combined via shfl_xor(1) at the end.
// One barrier per 32 edges; pp/srcs double-buffered. Block = 1 node.
// ---------------------------------------------------------------------------
__global__ __launch_bounds__(256) void attn7_kernel(const bf16* __restrict__ qkvs,
                                                    const int* __restrict__ off,
                                                    const int* __restrict__ csr_src,
                                                    bf16* __restrict__ out, int ostride) {
    __shared__ float pp[2][CH][9];
    __shared__ int srcs[2][CH];
    int i = blockIdx.x;
    int tid = threadIdx.x;
    int ea = tid >> 3, hA = tid & 7;                          // phase A
    int hc = tid >> 5, dp = (tid >> 1) & 15, epar = tid & 1;  // phase C

    // q fragment: head hA's 32 dims as 16 f16-pairs
    uint q2[16];
    {
        const uint4v* qp = (const uint4v*)(qkvs + (size_t)i * 1024 + hA * 32);
        uint4v a = qp[0], b = qp[1], c = qp[2], d = qp[3];
        q2[0] = a.x;  q2[1] = a.y;  q2[2] = a.z;  q2[3] = a.w;
        q2[4] = b.x;  q2[5] = b.y;  q2[6] = b.z;  q2[7] = b.w;
        q2[8] = c.x;  q2[9] = c.y;  q2[10] = c.z; q2[11] = c.w;
        q2[12] = d.x; q2[13] = d.y; q2[14] = d.z; q2[15] = d.w;
    }

    int e0 = off[i], e1 = off[i + 1];
    float l = 0.f, acc0 = 0.f, acc1 = 0.f;
    int vcol = 512 + hc * 32 + dp * 2;
    if (e0 < e1) {
        if (tid < CH) srcs[0][tid] = csr_src[min(e0 + tid, e1 - 1)];
        __syncthreads();
        int buf = 0;
        for (int base = e0; base < e1; base += CH, buf ^= 1) {
            int cnt = e1 - base;
            // ---- issue paired v loads (16 uints cover my 2 dims x 32 edges) ----
            uint vv[16];
            #pragma unroll
            for (int j = 0; j < 16; j++) {
                int e = epar + j * 2;
                vv[j] = *(const uint*)(qkvs + (size_t)srcs[buf][e] * 1024 + vcol);
            }
            // ---- A: full-head k load + 16 fdot2 + exp (no max, no shfl) ----
            int s = srcs[buf][ea];
            const uint4v* kp = (const uint4v*)(qkvs + (size_t)s * 1024 + 256 + hA * 32);
            uint4v ka = kp[0], kb = kp[1], kc = kp[2], kd = kp[3];
            // prefetch next chunk's srcs (32 threads, clamped)
            if (tid < CH) srcs[buf ^ 1][tid] = csr_src[min(base + CH + tid, e1 - 1)];
            float d = 0.f;
            d = dot2acc(q2[0], ka.x, d);  d = dot2acc(q2[1], ka.y, d);
            d = dot2acc(q2[2], ka.z, d);  d = dot2acc(q2[3], ka.w, d);
            d = dot2acc(q2[4], kb.x, d);  d = dot2acc(q2[5], kb.y, d);
            d = dot2acc(q2[6], kb.z, d);  d = dot2acc(q2[7], kb.w, d);
            d = dot2acc(q2[8], kc.x, d);  d = dot2acc(q2[9], kc.y, d);
            d = dot2acc(q2[10], kc.z, d); d = dot2acc(q2[11], kc.w, d);
            d = dot2acc(q2[12], kd.x, d); d = dot2acc(q2[13], kd.y, d);
            d = dot2acc(q2[14], kd.z, d); d = dot2acc(q2[15], kd.w, d);
            float p = (ea < cnt) ? __expf(d * 0.17677669529663687f) : 0.f;
            pp[buf][ea][hA] = p;
            __syncthreads();
            // ---- C: weighted V (my parity's 16 edges), l per-thread ----
            #pragma unroll
            for (int j = 0; j < 16; j++) {
                int e = epar + j * 2;
                float pj = pp[buf][e][hc];
                l += pj;
                union { uint i; float f; } lo, hi;
                lo.i = vv[j] << 16; hi.i = vv[j] & 0xffff0000u;
                acc0 += pj * lo.f;
                acc1 += pj * hi.f;
            }
        }
    }
    // combine edge parities (thread pair tid, tid^1)
    acc0 += __shfl_xor(acc0, 1);
    acc1 += __shfl_xor(acc1, 1);
    l    += __shfl_xor(l, 1);
    float inv = (l > 0.f) ? 1.f / l : 0.f;
    float r0 = acc0 * inv, r1 = acc1 * inv;
    if (epar == 0) {
        uint su = *(const uint*)(qkvs + (size_t)i * 1024 + 768 + hc * 32 + dp * 2);
        union { uint i; float f; } lo, hi;
        lo.i = su << 16; hi.i = su & 0xffff0000u;
        float v0 = fmaxf(r0 + lo.f, 0.f);
        float v1 = fmaxf(r1 + hi.f, 0.f);
        uint packed = ((uint)f2bfr(v1) << 16) | (uint)f2bfr(v0);
        *(uint*)(out + (size_t)i * ostride + hc * 32 + dp * 2) = packed;
    }
}

// ---------------------------------------------------------------------------
extern "C" void kernel_launch(void* const* d_in, const int* in_sizes, int n_in,
                              void* d_out, int out_size, void* d_ws, size_t ws_size,
                              hipStream_t stream) {
    const float* x      = (const float*)d_in[0];
    const int*   ei     = (const int*)d_in[1];
    const int*   batch  = (const int*)d_in[2];
    const float* s1_wl  = (const float*)d_in[3];
    const float* s1_bl  = (const float*)d_in[4];
    const float* s1_wr  = (const float*)d_in[5];
    const float* s2_wl  = (const float*)d_in[6];
    const float* s2_bl  = (const float*)d_in[7];
    const float* s2_wr  = (const float*)d_in[8];
    const float* t1_wq  = (const float*)d_in[9];
    const float* t1_bq  = (const float*)d_in[10];
    const float* t1_wk  = (const float*)d_in[11];
    const float* t1_bk  = (const float*)d_in[12];
    const float* t1_wv  = (const float*)d_in[13];
    const float* t1_bv  = (const float*)d_in[14];
    const float* t1_ws  = (const float*)d_in[15];
    const float* t1_bs  = (const float*)d_in[16];
    const float* t2_wq  = (const float*)d_in[17];
    const float* t2_bq  = (const float*)d_in[18];
    const float* t2_wk  = (const float*)d_in[19];
    const float* t2_bk  = (const float*)d_in[20];
    const float* t2_wv  = (const float*)d_in[21];
    const float* t2_bv  = (const float*)d_in[22];
    const float* t2_wsk = (const float*)d_in[23];
    const float* t2_bs  = (const float*)d_in[24];
    const float* p1_w   = (const float*)d_in[25];
    const float* p1_b   = (const float*)d_in[26];
    const float* p2_w   = (const float*)d_in[27];
    const float* p2_b   = (const float*)d_in[28];
    float* out = (float*)d_out;

    // ---- workspace layout ----
    char* ws = (char*)d_ws;
    size_t o = 0;
    auto alloc = [&](size_t bytes) { char* p = ws + o; o += (bytes + 255) & ~(size_t)255; return p; };
    int* off     = (int*)alloc(sizeof(int) * (NN + 1));
    int* cursor  = (int*)alloc(sizeof(int) * NN);
    int* csr_src = (int*)alloc(sizeof(int) * EE);
    bf16* w1cat = (bf16*)alloc(2 * 128 * 256);
    bf16* w2cat = (bf16*)alloc(2 * 256 * 256);
    bf16* qw1   = (bf16*)alloc(2 * 1024 * 256);
    bf16* qw2   = (bf16*)alloc(2 * 1024 * 256);
    bf16* p1t   = (bf16*)alloc(2 * 512 * 256);
    bf16* p2t   = (bf16*)alloc(2 * 128 * 512);
    float* qb1  = (float*)alloc(4 * 1024);
    float* qb2  = (float*)alloc(4 * 1024);
    bf16* xm1   = (bf16*)alloc(2 * (size_t)NN * 256);   // [x | mean(x)]; later h2/h4
    bf16* xm2   = (bf16*)alloc(2 * (size_t)NN * 256);   // [h1 | mean(h1)]
    bf16* t1b   = (bf16*)alloc(2 * (size_t)NN * 512);   // t1 (stride 256); later p1o
    bf16* Q     = (bf16*)alloc(2 * (size_t)NN * 1024);  // qkvs
    bf16* h2   = xm1;
    bf16* t1   = t1b;
    bf16* h4   = xm1;
    bf16* p1o  = t1b;

    const int* src = ei;
    const int* dst = ei + EE;

    // ---- memsets (cursor for CSR count; out for pool atomicMax) ----
    hipMemsetAsync(cursor, 0, sizeof(int) * NN, stream);
    hipMemsetAsync(out, 0, sizeof(float) * (size_t)out_size, stream);

    // ---- fused prep: conv x + tiled weight transpose + biases + CSR count ----
    prep_kernel<<<PREP_COUNT, 256, 0, stream>>>(
        x, xm1,
        s1_wr, s1_wl, s2_wr, s2_wl,
        t1_wq, t1_wk, t1_wv, t1_ws,
        t2_wq, t2_wk, t2_wv, t2_wsk,
        p1_w, p2_w,
        w1cat, w2cat, qw1, qw2, p1t, p2t,
        t1_bq, t1_bk, t1_bv, t1_bs,
        t2_bq, t2_bk, t2_bv, t2_bs,
        qb1, qb2,
        dst, cursor);

    // ---- CSR scan + fill ----
    scan_kernel<<<1, 1024, 0, stream>>>(cursor, off, NN);
    fill_kernel<<<(EE + 255) / 256, 256, 0, stream>>>(src, dst, cursor, csr_src, EE);

    // ---- SAGE 1: h1 = relu([x|mean(x)] @ w1cat + bl) -> xm2 first half ----
    mean2_kernel<<<NN / 4, 256, 0, stream>>>(xm1, 256, off, csr_src, xm1 + 128, 256);
    launch_gemm<2, 64>(xm1, w1cat, s1_bl, xm2, NN, 256, 128, 256, stream);

    // ---- SAGE 2: h2 = relu([h1|mean(h1)] @ w2cat + bl) ----
    mean2_kernel<<<NN / 4, 256, 0, stream>>>(xm2, 256, off, csr_src, xm2 + 128, 256);
    launch_gemm<2, 64>(xm2, w2cat, s2_bl, h2, NN, 256, 256, 256, stream);

    // ---- TransformerConv 1 (qkvs GEMM stores q,k f16 / v,skip bf16) ----
    launch_gemm<5, 128>(h2, qw1, qb1, Q, NN, 256, 1024, 1024, stream);
    attn7_kernel<<<NN, 256, 0, stream>>>(Q, off, csr_src, t1, 256);

    // ---- TransformerConv 2 ----
    launch_gemm<5, 128>(t1, qw2, qb2, Q, NN, 256, 1024, 1024, stream);
    attn7_kernel<<<NN, 256, 0, stream>>>(Q, off, csr_src, h4, 256);

    // ---- proj MLP (p2 fuses sigmoid + grouped max pool) ----
    launch_gemm<2, 128>(h4, p1t, p1_b, p1o, NN, 256, 512, 512, stream);
    launch_gemm<4, 64>(p1o, p2t, p2_b, nullptr, NN, 512, 128, 128, stream, batch, out);
}

// Round 12
// 417.424 us; speedup vs baseline: 1.1248x; 1.1248x over previous
//
#include <hip/hip_runtime.h>
#include <hip/hip_bf16.h>
#include <hip/hip_fp16.h>
#include <math.h>

#define NN 20000
#define EE 320000
#define GG 64
#define CH 16   // attention chunk size (edges)

typedef __hip_bfloat16 bf16;
typedef __attribute__((ext_vector_type(8))) short short8;
typedef __attribute__((ext_vector_type(4))) float f32x4;
typedef __attribute__((ext_vector_type(4))) unsigned int uint4v;
typedef __attribute__((ext_vector_type(2))) _Float16 half2v;
typedef unsigned int uint;
typedef unsigned short ushort;

__device__ __forceinline__ float bfr2f(ushort u) {
    union { uint i; float f; } c; c.i = ((uint)u) << 16; return c.f;
}
__device__ __forceinline__ ushort f2bfr(float f) {
    bf16 h = __float2bfloat16(f);
    return *(ushort*)&h;
}

// fp16-pair dot with f32 accumulate: c + a.x*b.x + a.y*b.y
__device__ __forceinline__ float dot2acc(uint a, uint b, float c) {
#if __has_builtin(__builtin_amdgcn_fdot2)
    return __builtin_amdgcn_fdot2(__builtin_bit_cast(half2v, a),
                                  __builtin_bit_cast(half2v, b), c, false);
#else
    half2v ha = __builtin_bit_cast(half2v, a);
    half2v hb = __builtin_bit_cast(half2v, b);
    return c + (float)ha.x * (float)hb.x + (float)ha.y * (float)hb.y;
#endif
}

// ---------------------------------------------------------------------------
// async global->LDS 16B copy
// ---------------------------------------------------------------------------
__device__ __forceinline__ void load_lds16(const void* g, void* l) {
    __builtin_amdgcn_global_load_lds(
        (const __attribute__((address_space(1))) unsigned int*)g,
        (__attribute__((address_space(3))) unsigned int*)l, 16, 0, 0);
}

// ---------------------------------------------------------------------------
// fused prep: x->bf16 (strided), LDS-tiled weight transposes, biases, count,
// and pool-output zeroing.
// ---------------------------------------------------------------------------
#define PREP_CONV  10000                 // NN*128/256 blocks: x convert
#define PREP_TP    (PREP_CONV + 800)     // 800 32x32 transpose tiles
#define PREP_BIAS  (PREP_TP + 8)
#define PREP_OUTZ  (PREP_BIAS + 32)      // zero GG*128 pool output
#define PREP_COUNT (PREP_OUTZ + 1250)

__global__ __launch_bounds__(256) void prep_kernel(
    const float* x, bf16* xm1,
    const float* s1_wr, const float* s1_wl, const float* s2_wr, const float* s2_wl,
    const float* t1_wq, const float* t1_wk, const float* t1_wv, const float* t1_ws,
    const float* t2_wq, const float* t2_wk, const float* t2_wv, const float* t2_ws,
    const float* p1_w, const float* p2_w,
    bf16* w1cat, bf16* w2cat, bf16* qw1, bf16* qw2, bf16* p1t, bf16* p2t,
    const float* b1q, const float* b1k, const float* b1v, const float* b1s,
    const float* b2q, const float* b2k, const float* b2v, const float* b2s,
    float* qb1, float* qb2,
    float* pool_out,
    const int* dst, int* cnt) {
    __shared__ float tile[32][33];
    int bid = blockIdx.x;
    int tid = threadIdx.x;
    if (bid < PREP_CONV) {
        int i = bid * 256 + tid;  // < NN*128
        int r = i >> 7, c = i & 127;
        xm1[(size_t)r * 256 + c] = __float2bfloat16(x[i]);
    } else if (bid < PREP_TP) {
        // ---- LDS-tiled transpose: Wt[n][KOFF+k] = bf16(W[k][n]) ----
        int tb = bid - PREP_CONV;   // 0..799
        const float* W; bf16* Wt; int KW, NW, KT, KO, lt;
        const float* t1w[4] = {t1_wq, t1_wk, t1_wv, t1_ws};
        const float* t2w[4] = {t2_wq, t2_wk, t2_wv, t2_ws};
        if (tb < 16)       { W = s1_wr; Wt = w1cat; KW = 128; NW = 128; KT = 256; KO = 0;   lt = tb; }
        else if (tb < 32)  { W = s1_wl; Wt = w1cat; KW = 128; NW = 128; KT = 256; KO = 128; lt = tb - 16; }
        else if (tb < 64)  { W = s2_wr; Wt = w2cat; KW = 128; NW = 256; KT = 256; KO = 0;   lt = tb - 32; }
        else if (tb < 96)  { W = s2_wl; Wt = w2cat; KW = 128; NW = 256; KT = 256; KO = 128; lt = tb - 64; }
        else if (tb < 352) { int m = (tb - 96) >> 6;  W = t1w[m]; Wt = qw1 + m * 65536; KW = 256; NW = 256; KT = 256; KO = 0; lt = (tb - 96) & 63; }
        else if (tb < 608) { int m = (tb - 352) >> 6; W = t2w[m]; Wt = qw2 + m * 65536; KW = 256; NW = 256; KT = 256; KO = 0; lt = (tb - 352) & 63; }
        else if (tb < 736) { W = p1_w; Wt = p1t; KW = 256; NW = 512; KT = 256; KO = 0; lt = tb - 608; }
        else               { W = p2_w; Wt = p2t; KW = 512; NW = 128; KT = 512; KO = 0; lt = tb - 736; }
        int ntiles_n = NW >> 5;
        int k0 = (lt / ntiles_n) * 32;
        int n0 = (lt % ntiles_n) * 32;
        int tx = tid & 31, ty = tid >> 5;   // ty 0..7
        #pragma unroll
        for (int r = 0; r < 4; r++)
            tile[ty + 8 * r][tx] = W[(size_t)(k0 + ty + 8 * r) * NW + n0 + tx];
        __syncthreads();
        #pragma unroll
        for (int r = 0; r < 4; r++)
            Wt[(size_t)(n0 + ty + 8 * r) * KT + KO + k0 + tx] =
                __float2bfloat16(tile[tx][ty + 8 * r]);
    } else if (bid < PREP_BIAS) {
        int i = (bid - PREP_TP) * 256 + tid;
        if (i < 2048) {
            float* d = (i < 1024) ? qb1 : qb2;
            int j = i & 1023;
            const float* s;
            if (i < 1024) s = (j < 256) ? b1q : (j < 512) ? b1k : (j < 768) ? b1v : b1s;
            else          s = (j < 256) ? b2q : (j < 512) ? b2k : (j < 768) ? b2v : b2s;
            d[j] = s[j & 255];
        }
    } else if (bid < PREP_OUTZ) {
        int i = (bid - PREP_BIAS) * 256 + tid;
        if (i < GG * 128) pool_out[i] = 0.f;
    } else {
        int e = (bid - PREP_OUTZ) * 256 + tid;
        if (e < EE) atomicAdd(&cnt[dst[e]], 1);
    }
}

// ---------------------------------------------------------------------------
// scan: shfl-based wave scan. cnt -> off (excl), cursor.
// ---------------------------------------------------------------------------
__global__ __launch_bounds__(1024) void scan_kernel(int* __restrict__ cnt,
                                                    int* __restrict__ off, int n) {
    __shared__ int wsum[16];
    __shared__ int carry_s;
    int tid = threadIdx.x;
    int lane = tid & 63, wid = tid >> 6;
    if (tid == 0) { carry_s = 0; off[0] = 0; }
    __syncthreads();
    for (int base = 0; base < n; base += 1024) {
        int idx = base + tid;
        int val = (idx < n) ? cnt[idx] : 0;
        int x = val;
        #pragma unroll
        for (int s = 1; s < 64; s <<= 1) {
            int y = __shfl_up(x, s, 64);
            if (lane >= s) x += y;
        }
        if (lane == 63) wsum[wid] = x;
        __syncthreads();
        if (tid == 0) {
            int c = carry_s;
            #pragma unroll
            for (int w = 0; w < 16; w++) { int t = wsum[w]; wsum[w] = c; c += t; }
            carry_s = c;
        }
        __syncthreads();
        int incl = wsum[wid] + x;
        if (idx < n) {
            off[idx + 1] = incl;
            cnt[idx] = incl - val;
        }
        __syncthreads();
    }
}

__global__ __launch_bounds__(256) void fill_kernel(const int* __restrict__ src,
                                                   const int* __restrict__ dst,
                                                   int* __restrict__ cursor,
                                                   int* __restrict__ csr_src, int E) {
    int e = blockIdx.x * 256 + threadIdx.x;
    if (e < E) {
        int p = atomicAdd(&cursor[dst[e]], 1);
        csr_src[p] = src[e];
    }
}

// ---------------------------------------------------------------------------
// Mean aggregation: 4 nodes/block, 1 wave/node, bf16x2/lane, unroll x8.
// ---------------------------------------------------------------------------
__global__ __launch_bounds__(256) void mean2_kernel(const bf16* __restrict__ x, int xstride,
                                                    const int* __restrict__ off,
                                                    const int* __restrict__ csr_src,
                                                    bf16* __restrict__ outp, int ostride) {
    int node = blockIdx.x * 4 + (threadIdx.x >> 6);
    int lane = threadIdx.x & 63;
    int e0 = off[node], e1 = off[node + 1];
    float s0 = 0.f, s1 = 0.f;
    int e = e0;
    for (; e + 7 < e1; e += 8) {
        uint a[8];
        #pragma unroll
        for (int j = 0; j < 8; j++) {
            int sa = csr_src[e + j];
            a[j] = *(const uint*)(x + (size_t)sa * xstride + lane * 2);
        }
        #pragma unroll
        for (int j = 0; j < 8; j++) {
            union { uint i; float f; } t;
            t.i = a[j] << 16; s0 += t.f;
            t.i = a[j] & 0xffff0000u; s1 += t.f;
        }
    }
    for (; e < e1; e++) {
        int sa = csr_src[e];
        uint a = *(const uint*)(x + (size_t)sa * xstride + lane * 2);
        union { uint i; float f; } t;
        t.i = a << 16; s0 += t.f; t.i = a & 0xffff0000u; s1 += t.f;
    }
    int deg = e1 - e0;
    float inv = (deg > 0) ? 1.f / (float)deg : 0.f;
    uint r = ((uint)f2bfr(s1 * inv) << 16) | (uint)f2bfr(s0 * inv);
    *(uint*)(outp + (size_t)node * ostride + lane * 2) = r;
}

// ---------------------------------------------------------------------------
// bf16 MFMA GEMM: C[M,N] = A[M,K] @ Wt[N,K]^T, fused epilogue. BK=64.
// XOR-swizzled LDS: slot (row, c) holds global 16B-chunk (c ^ (row&7)) —
// kills the 8-way bank conflict of the 128B-row layout while keeping the
// lane-contiguous destination global_load_lds requires (swizzle applied to
// the global SOURCE address; cacheline set unchanged -> coalescing intact).
// MODE 2: relu(+bias), bf16.
// MODE 5: +bias; store f16 for gn<512 (q,k), bf16 else (v,skip)  [qkvs]
// MODE 4: sigmoid(+bias) then grouped max-pool (sorted batch) -> ~1 atomic/col.
// ---------------------------------------------------------------------------
template <int MODE, int TM>
__global__ __launch_bounds__(256, (TM == 128) ? 3 : 4)
void gemm_kernel(const bf16* __restrict__ A,
                 const bf16* __restrict__ Wt,
                 const float* __restrict__ bias,
                 void* __restrict__ Cv,
                 int M, int K, int N, int cstride,
                 const int* __restrict__ batch,
                 float* __restrict__ pool_out) {
    constexpr int NT = (TM == 128) ? 4 : 2;   // n-tiles per wave
    __shared__ short As[TM * 64];
    __shared__ short Bs[128 * 64];
    __shared__ int bat[TM];
    int t = threadIdx.x;
    int lane = t & 63;
    int wave = t >> 6;
    int wm = (TM == 128) ? (wave >> 1) * 64 : 0;
    int wn = (TM == 128) ? (wave & 1) * 64 : wave * 32;
    int bm = blockIdx.y * TM, bn = blockIdx.x * 128;
    int quad = lane >> 4, l16 = lane & 15;
    int srow = t >> 3;                       // 32 staging rows per round
    int sc8  = t & 7;                        // LDS chunk slot (16B units)
    int scol = sc8 * 8;                      // LDS offset (shorts)
    int gcol = (sc8 ^ (srow & 7)) * 8;       // swizzled global chunk offset
    int sw   = l16 & 7;                      // read-side swizzle key

    if (MODE == 4 && t < TM) bat[t] = batch[min(bm + t, M - 1)];

    f32x4 acc[4][NT];
    f32x4 zero = {0.f, 0.f, 0.f, 0.f};
    #pragma unroll
    for (int i = 0; i < 4; i++)
        #pragma unroll
        for (int j = 0; j < NT; j++) acc[i][j] = zero;

    for (int kk = 0; kk < K; kk += 64) {
        #pragma unroll
        for (int r = 0; r < TM / 32; r++) {
            int row = r * 32 + srow;         // (row&7)==(srow&7): gcol valid
            int gm = bm + row; gm = (gm < M) ? gm : (M - 1);
            load_lds16(A + (size_t)gm * K + kk + gcol, &As[row * 64 + scol]);
        }
        #pragma unroll
        for (int r = 0; r < 4; r++) {
            int row = r * 32 + srow;
            load_lds16(Wt + (size_t)(bn + row) * K + kk + gcol, &Bs[row * 64 + scol]);
        }
        __syncthreads();
        #pragma unroll
        for (int ks = 0; ks < 2; ks++) {
            short8 af[4], bfr[NT];
            #pragma unroll
            for (int i = 0; i < 4; i++)
                af[i] = *(const short8*)&As[(wm + i * 16 + l16) * 64 + ((ks * 4 + quad) ^ sw) * 8];
            #pragma unroll
            for (int j = 0; j < NT; j++)
                bfr[j] = *(const short8*)&Bs[(wn + j * 16 + l16) * 64 + ((ks * 4 + quad) ^ sw) * 8];
            #pragma unroll
            for (int i = 0; i < 4; i++)
                #pragma unroll
                for (int j = 0; j < NT; j++)
                    acc[i][j] = __builtin_amdgcn_mfma_f32_16x16x32_bf16(af[i], bfr[j], acc[i][j], 0, 0, 0);
        }
        __syncthreads();
    }

    if (MODE == 4) {
        int g0 = bat[0], gL = bat[TM - 1];
        #pragma unroll
        for (int j = 0; j < NT; j++) {
            int gn = bn + wn + j * 16 + l16;
            float m0 = 0.f, m1 = 0.f;
            #pragma unroll
            for (int i = 0; i < 4; i++) {
                #pragma unroll
                for (int r = 0; r < 4; r++) {
                    int row = i * 16 + quad * 4 + r;
                    int gm = bm + row;
                    if (gm >= M) continue;
                    float v = acc[i][j][r] + bias[gn];
                    v = 1.f / (1.f + expf(-v));
                    int g = bat[row];
                    if (g == g0) m0 = fmaxf(m0, v);
                    else if (g == gL) m1 = fmaxf(m1, v);
                    else atomicMax((int*)&pool_out[g * 128 + gn], __float_as_int(v));
                }
            }
            m0 = fmaxf(m0, __shfl_xor(m0, 16));
            m0 = fmaxf(m0, __shfl_xor(m0, 32));
            m1 = fmaxf(m1, __shfl_xor(m1, 16));
            m1 = fmaxf(m1, __shfl_xor(m1, 32));
            if (quad == 0) {
                atomicMax((int*)&pool_out[g0 * 128 + gn], __float_as_int(m0));
                if (gL != g0)
                    atomicMax((int*)&pool_out[gL * 128 + gn], __float_as_int(m1));
            }
        }
        return;
    }

    // epilogue: C/D layout col=lane&15, row=quad*4+reg
    #pragma unroll
    for (int i = 0; i < 4; i++) {
        int gm0 = bm + wm + i * 16 + quad * 4;
        #pragma unroll
        for (int j = 0; j < NT; j++) {
            int gn = bn + wn + j * 16 + l16;
            #pragma unroll
            for (int r = 0; r < 4; r++) {
                int gm = gm0 + r;
                if (gm >= M) continue;
                float v = acc[i][j][r] + bias[gn];
                if (MODE == 2) v = fmaxf(v, 0.f);
                ushort st;
                if (MODE == 5 && gn < 512) {
                    __half hh = __float2half(v);
                    st = *(ushort*)&hh;
                } else {
                    st = f2bfr(v);
                }
                ((ushort*)Cv)[(size_t)gm * cstride + gn] = st;
            }
        }
    }
}

template <int MODE, int TM>
static void launch_gemm(const bf16* A, const bf16* Wt, const float* bias, void* C,
                        int M, int K, int N, int cstride, hipStream_t st,
                        const int* batch = nullptr, float* pool_out = nullptr) {
    dim3 grid(N / 128, (M + TM - 1) / TM);
    hipLaunchKernelGGL((gemm_kernel<MODE, TM>), grid, dim3(256), 0, st,
                       A, Wt, bias, C, M, K, N, cstride, batch, pool_out);
}

// ---------------------------------------------------------------------------
// TransformerConv attention v5 (R8/R10-proven): no-max softmax, pipelined
// chunks, f16 q/k dot via v_dot2_f32_f16, paired (uint) v loads.
// qkvs row stride 1024: [q f16(256) k f16(256) v bf16(256) skip bf16(256)].
// ---------------------------------------------------------------------------
__global__ __launch_bounds__(256) void attn5_kernel(const bf16* __restrict__ qkvs,
                                                    const int* __restrict__ off,
                                                    const int* __restrict__ csr_src,
                                                    bf16* __restrict__ out, int ostride) {
    __shared__ float pp[2][CH][9];
    __shared__ int srcs[2][CH];
    int i = blockIdx.x;
    int tid = threadIdx.x;
    int ea = tid >> 4, ha = (tid >> 1) & 7, half = tid & 1;   // phase A
    int hc = tid >> 5, dp = (tid >> 1) & 15, epar = tid & 1;  // phase C

    // q fragment: 16 dims as 8 half2 pairs
    uint q2[8];
    {
        const uint4v* qp = (const uint4v*)(qkvs + (size_t)i * 1024 + ha * 32 + half * 16);
        uint4v a = qp[0], b = qp[1];
        q2[0] = a.x; q2[1] = a.y; q2[2] = a.z; q2[3] = a.w;
        q2[4] = b.x; q2[5] = b.y; q2[6] = b.z; q2[7] = b.w;
    }

    int e0 = off[i], e1 = off[i + 1];
    float l = 0.f, acc0 = 0.f, acc1 = 0.f;
    int vcol = 512 + hc * 32 + dp * 2;
    if (e0 < e1) {
        if (tid < CH) srcs[0][tid] = csr_src[min(e0 + tid, e1 - 1)];
        __syncthreads();
        int buf = 0;
        for (int base = e0; base < e1; base += CH, buf ^= 1) {
            int cnt = min(CH, e1 - base);
            // ---- issue paired v loads (8 uints cover my 2 dims x 16 edges) ----
            uint vv[8];
            #pragma unroll
            for (int j = 0; j < 8; j++) {
                int e = epar + j * 2;
                vv[j] = *(const uint*)(qkvs + (size_t)srcs[buf][e] * 1024 + vcol);
            }
            // ---- A: k load + fdot2 chain + exp (no max) ----
            int s = srcs[buf][ea];
            const uint4v* kp = (const uint4v*)(qkvs + (size_t)s * 1024 + 256 + ha * 32 + half * 16);
            uint4v ka = kp[0], kb = kp[1];
            // prefetch next chunk's srcs (16 threads, clamped)
            if (tid < CH) srcs[buf ^ 1][tid] = csr_src[min(base + CH + tid, e1 - 1)];
            float d = 0.f;
            d = dot2acc(q2[0], ka.x, d); d = dot2acc(q2[1], ka.y, d);
            d = dot2acc(q2[2], ka.z, d); d = dot2acc(q2[3], ka.w, d);
            d = dot2acc(q2[4], kb.x, d); d = dot2acc(q2[5], kb.y, d);
            d = dot2acc(q2[6], kb.z, d); d = dot2acc(q2[7], kb.w, d);
            d += __shfl_xor(d, 1);
            float p = (ea < cnt) ? __expf(d * 0.17677669529663687f) : 0.f;
            if (half == 0) pp[buf][ea][ha] = p;
            __syncthreads();
            // ---- C: weighted V (my parity's 8 edges), l per-thread ----
            #pragma unroll
            for (int j = 0; j < 8; j++) {
                int e = epar + j * 2;
                float pj = pp[buf][e][hc];
                l += pj;
                union { uint i; float f; } lo, hi;
                lo.i = vv[j] << 16; hi.i = vv[j] & 0xffff0000u;
                acc0 += pj * lo.f;
                acc1 += pj * hi.f;
            }
        }
    }
    // combine edge parities (thread pair tid, tid^1)
    acc0 += __shfl_xor(acc0, 1);
    acc1 += __shfl_xor(acc1, 1);
    l    += __shfl_xor(l, 1);
    float inv = (l > 0.f) ? 1.f / l : 0.f;
    float r0 = acc0 * inv, r1 = acc1 * inv;
    if (epar == 0) {
        uint su = *(const uint*)(qkvs + (size_t)i * 1024 + 768 + hc * 32 + dp * 2);
        union { uint i; float f; } lo, hi;
        lo.i = su << 16; hi.i = su & 0xffff0000u;
        float v0 = fmaxf(r0 + lo.f, 0.f);
        float v1 = fmaxf(r1 + hi.f, 0.f);
        uint packed = ((uint)f2bfr(v1) << 16) | (uint)f2bfr(v0);
        *(uint*)(out + (size_t)i * ostride + hc * 32 + dp * 2) = packed;
    }
}

// ---------------------------------------------------------------------------
extern "C" void kernel_launch(void* const* d_in, const int* in_sizes, int n_in,
                              void* d_out, int out_size, void* d_ws, size_t ws_size,
                              hipStream_t stream) {
    const float* x      = (const float*)d_in[0];
    const int*   ei     = (const int*)d_in[1];
    const int*   batch  = (const int*)d_in[2];
    const float* s1_wl  = (const float*)d_in[3];
    const float* s1_bl  = (const float*)d_in[4];
    const float* s1_wr  = (const float*)d_in[5];
    const float* s2_wl  = (const float*)d_in[6];
    const float* s2_bl  = (const float*)d_in[7];
    const float* s2_wr  = (const float*)d_in[8];
    const float* t1_wq  = (const float*)d_in[9];
    const float* t1_bq  = (const float*)d_in[10];
    const float* t1_wk  = (const float*)d_in[11];
    const float* t1_bk  = (const float*)d_in[12];
    const float* t1_wv  = (const float*)d_in[13];
    const float* t1_bv  = (const float*)d_in[14];
    const float* t1_ws  = (const float*)d_in[15];
    const float* t1_bs  = (const float*)d_in[16];
    const float* t2_wq  = (const float*)d_in[17];
    const float* t2_bq  = (const float*)d_in[18];
    const float* t2_wk  = (const float*)d_in[19];
    const float* t2_bk  = (const float*)d_in[20];
    const float* t2_wv  = (const float*)d_in[21];
    const float* t2_bv  = (const float*)d_in[22];
    const float* t2_wsk = (const float*)d_in[23];
    const float* t2_bs  = (const float*)d_in[24];
    const float* p1_w   = (const float*)d_in[25];
    const float* p1_b   = (const float*)d_in[26];
    const float* p2_w   = (const float*)d_in[27];
    const float* p2_b   = (const float*)d_in[28];
    float* out = (float*)d_out;

    // ---- workspace layout ----
    char* ws = (char*)d_ws;
    size_t o = 0;
    auto alloc = [&](size_t bytes) { char* p = ws + o; o += (bytes + 255) & ~(size_t)255; return p; };
    int* off     = (int*)alloc(sizeof(int) * (NN + 1));
    int* cursor  = (int*)alloc(sizeof(int) * NN);
    int* csr_src = (int*)alloc(sizeof(int) * EE);
    bf16* w1cat = (bf16*)alloc(2 * 128 * 256);
    bf16* w2cat = (bf16*)alloc(2 * 256 * 256);
    bf16* qw1   = (bf16*)alloc(2 * 1024 * 256);
    bf16* qw2   = (bf16*)alloc(2 * 1024 * 256);
    bf16* p1t   = (bf16*)alloc(2 * 512 * 256);
    bf16* p2t   = (bf16*)alloc(2 * 128 * 512);
    float* qb1  = (float*)alloc(4 * 1024);
    float* qb2  = (float*)alloc(4 * 1024);
    bf16* xm1   = (bf16*)alloc(2 * (size_t)NN * 256);   // [x | mean(x)]; later h2/h4
    bf16* xm2   = (bf16*)alloc(2 * (size_t)NN * 256);   // [h1 | mean(h1)]
    bf16* t1b   = (bf16*)alloc(2 * (size_t)NN * 512);   // t1 (stride 256); later p1o
    bf16* Q     = (bf16*)alloc(2 * (size_t)NN * 1024);  // qkvs
    bf16* h2   = xm1;
    bf16* t1   = t1b;
    bf16* h4   = xm1;
    bf16* p1o  = t1b;

    const int* src = ei;
    const int* dst = ei + EE;

    // ---- memset (cursor for CSR count; pool-out zeroed inside prep) ----
    hipMemsetAsync(cursor, 0, sizeof(int) * NN, stream);

    // ---- fused prep: conv x + tiled transpose + biases + out-zero + count ----
    prep_kernel<<<PREP_COUNT, 256, 0, stream>>>(
        x, xm1,
        s1_wr, s1_wl, s2_wr, s2_wl,
        t1_wq, t1_wk, t1_wv, t1_ws,
        t2_wq, t2_wk, t2_wv, t2_wsk,
        p1_w, p2_w,
        w1cat, w2cat, qw1, qw2, p1t, p2t,
        t1_bq, t1_bk, t1_bv, t1_bs,
        t2_bq, t2_bk, t2_bv, t2_bs,
        qb1, qb2,
        out,
        dst, cursor);

    // ---- CSR scan + fill ----
    scan_kernel<<<1, 1024, 0, stream>>>(cursor, off, NN);
    fill_kernel<<<(EE + 255) / 256, 256, 0, stream>>>(src, dst, cursor, csr_src, EE);

    // ---- SAGE 1: h1 = relu([x|mean(x)] @ w1cat + bl) -> xm2 first half ----
    mean2_kernel<<<NN / 4, 256, 0, stream>>>(xm1, 256, off, csr_src, xm1 + 128, 256);
    launch_gemm<2, 64>(xm1, w1cat, s1_bl, xm2, NN, 256, 128, 256, stream);

    // ---- SAGE 2: h2 = relu([h1|mean(h1)] @ w2cat + bl) ----
    mean2_kernel<<<NN / 4, 256, 0, stream>>>(xm2, 256, off, csr_src, xm2 + 128, 256);
    launch_gemm<2, 64>(xm2, w2cat, s2_bl, h2, NN, 256, 256, 256, stream);

    // ---- TransformerConv 1 (qkvs GEMM stores q,k f16 / v,skip bf16) ----
    launch_gemm<5, 128>(h2, qw1, qb1, Q, NN, 256, 1024, 1024, stream);
    attn5_kernel<<<NN, 256, 0, stream>>>(Q, off, csr_src, t1, 256);

    // ---- TransformerConv 2 ----
    launch_gemm<5, 128>(t1, qw2, qb2, Q, NN, 256, 1024, 1024, stream);
    attn5_kernel<<<NN, 256, 0, stream>>>(Q, off, csr_src, h4, 256);

    // ---- proj MLP (p2 fuses sigmoid + grouped max pool) ----
    launch_gemm<2, 128>(h4, p1t, p1_b, p1o, NN, 256, 512, 512, stream);
    launch_gemm<4, 64>(p1o, p2t, p2_b, nullptr, NN, 512, 128, 128, stream, batch, out);
}

// Round 13
// 380.381 us; speedup vs baseline: 1.2343x; 1.0974x over previous
//
#include <hip/hip_runtime.h>
#include <hip/hip_bf16.h>
#include <hip/hip_fp16.h>
#include <math.h>

#define NN 20000
#define EE 320000
#define GG 64
#define CH 16   // attention chunk size (edges)

typedef __hip_bfloat16 bf16;
typedef __attribute__((ext_vector_type(8))) short short8;
typedef __attribute__((ext_vector_type(4))) float f32x4;
typedef __attribute__((ext_vector_type(4))) unsigned int uint4v;
typedef __attribute__((ext_vector_type(2))) _Float16 half2v;
typedef unsigned int uint;
typedef unsigned short ushort;

__device__ __forceinline__ float bfr2f(ushort u) {
    union { uint i; float f; } c; c.i = ((uint)u) << 16; return c.f;
}
__device__ __forceinline__ ushort f2bfr(float f) {
    bf16 h = __float2bfloat16(f);
    return *(ushort*)&h;
}

// fp16-pair dot with f32 accumulate: c + a.x*b.x + a.y*b.y
__device__ __forceinline__ float dot2acc(uint a, uint b, float c) {
#if __has_builtin(__builtin_amdgcn_fdot2)
    return __builtin_amdgcn_fdot2(__builtin_bit_cast(half2v, a),
                                  __builtin_bit_cast(half2v, b), c, false);
#else
    half2v ha = __builtin_bit_cast(half2v, a);
    half2v hb = __builtin_bit_cast(half2v, b);
    return c + (float)ha.x * (float)hb.x + (float)ha.y * (float)hb.y;
#endif
}

// ---------------------------------------------------------------------------
// async global->LDS 16B copy
// ---------------------------------------------------------------------------
__device__ __forceinline__ void load_lds16(const void* g, void* l) {
    __builtin_amdgcn_global_load_lds(
        (const __attribute__((address_space(1))) unsigned int*)g,
        (__attribute__((address_space(3))) unsigned int*)l, 16, 0, 0);
}

// ---------------------------------------------------------------------------
// fused prep: x->bf16 (strided), LDS-tiled weight transposes, biases, count,
// and pool-output zeroing.
// ---------------------------------------------------------------------------
#define PREP_CONV  10000                 // NN*128/256 blocks: x convert
#define PREP_TP    (PREP_CONV + 800)     // 800 32x32 transpose tiles
#define PREP_BIAS  (PREP_TP + 8)
#define PREP_OUTZ  (PREP_BIAS + 32)      // zero GG*128 pool output
#define PREP_COUNT (PREP_OUTZ + 1250)

__global__ __launch_bounds__(256) void prep_kernel(
    const float* x, bf16* xm1,
    const float* s1_wr, const float* s1_wl, const float* s2_wr, const float* s2_wl,
    const float* t1_wq, const float* t1_wk, const float* t1_wv, const float* t1_ws,
    const float* t2_wq, const float* t2_wk, const float* t2_wv, const float* t2_ws,
    const float* p1_w, const float* p2_w,
    bf16* w1cat, bf16* w2cat, bf16* qw1, bf16* qw2, bf16* p1t, bf16* p2t,
    const float* b1q, const float* b1k, const float* b1v, const float* b1s,
    const float* b2q, const float* b2k, const float* b2v, const float* b2s,
    float* qb1, float* qb2,
    float* pool_out,
    const int* dst, int* cnt) {
    __shared__ float tile[32][33];
    int bid = blockIdx.x;
    int tid = threadIdx.x;
    if (bid < PREP_CONV) {
        int i = bid * 256 + tid;  // < NN*128
        int r = i >> 7, c = i & 127;
        xm1[(size_t)r * 256 + c] = __float2bfloat16(x[i]);
    } else if (bid < PREP_TP) {
        // ---- LDS-tiled transpose: Wt[n][KOFF+k] = bf16(W[k][n]) ----
        int tb = bid - PREP_CONV;   // 0..799
        const float* W; bf16* Wt; int KW, NW, KT, KO, lt;
        const float* t1w[4] = {t1_wq, t1_wk, t1_wv, t1_ws};
        const float* t2w[4] = {t2_wq, t2_wk, t2_wv, t2_ws};
        if (tb < 16)       { W = s1_wr; Wt = w1cat; KW = 128; NW = 128; KT = 256; KO = 0;   lt = tb; }
        else if (tb < 32)  { W = s1_wl; Wt = w1cat; KW = 128; NW = 128; KT = 256; KO = 128; lt = tb - 16; }
        else if (tb < 64)  { W = s2_wr; Wt = w2cat; KW = 128; NW = 256; KT = 256; KO = 0;   lt = tb - 32; }
        else if (tb < 96)  { W = s2_wl; Wt = w2cat; KW = 128; NW = 256; KT = 256; KO = 128; lt = tb - 64; }
        else if (tb < 352) { int m = (tb - 96) >> 6;  W = t1w[m]; Wt = qw1 + m * 65536; KW = 256; NW = 256; KT = 256; KO = 0; lt = (tb - 96) & 63; }
        else if (tb < 608) { int m = (tb - 352) >> 6; W = t2w[m]; Wt = qw2 + m * 65536; KW = 256; NW = 256; KT = 256; KO = 0; lt = (tb - 352) & 63; }
        else if (tb < 736) { W = p1_w; Wt = p1t; KW = 256; NW = 512; KT = 256; KO = 0; lt = tb - 608; }
        else               { W = p2_w; Wt = p2t; KW = 512; NW = 128; KT = 512; KO = 0; lt = tb - 736; }
        int ntiles_n = NW >> 5;
        int k0 = (lt / ntiles_n) * 32;
        int n0 = (lt % ntiles_n) * 32;
        int tx = tid & 31, ty = tid >> 5;   // ty 0..7
        #pragma unroll
        for (int r = 0; r < 4; r++)
            tile[ty + 8 * r][tx] = W[(size_t)(k0 + ty + 8 * r) * NW + n0 + tx];
        __syncthreads();
        #pragma unroll
        for (int r = 0; r < 4; r++)
            Wt[(size_t)(n0 + ty + 8 * r) * KT + KO + k0 + tx] =
                __float2bfloat16(tile[tx][ty + 8 * r]);
    } else if (bid < PREP_BIAS) {
        int i = (bid - PREP_TP) * 256 + tid;
        if (i < 2048) {
            float* d = (i < 1024) ? qb1 : qb2;
            int j = i & 1023;
            const float* s;
            if (i < 1024) s = (j < 256) ? b1q : (j < 512) ? b1k : (j < 768) ? b1v : b1s;
            else          s = (j < 256) ? b2q : (j < 512) ? b2k : (j < 768) ? b2v : b2s;
            d[j] = s[j & 255];
        }
    } else if (bid < PREP_OUTZ) {
        int i = (bid - PREP_BIAS) * 256 + tid;
        if (i < GG * 128) pool_out[i] = 0.f;
    } else {
        int e = (bid - PREP_OUTZ) * 256 + tid;
        if (e < EE) atomicAdd(&cnt[dst[e]], 1);
    }
}

// ---------------------------------------------------------------------------
// scan: shfl-based wave scan. cnt -> off (excl), cursor.
// ---------------------------------------------------------------------------
__global__ __launch_bounds__(1024) void scan_kernel(int* __restrict__ cnt,
                                                    int* __restrict__ off, int n) {
    __shared__ int wsum[16];
    __shared__ int carry_s;
    int tid = threadIdx.x;
    int lane = tid & 63, wid = tid >> 6;
    if (tid == 0) { carry_s = 0; off[0] = 0; }
    __syncthreads();
    for (int base = 0; base < n; base += 1024) {
        int idx = base + tid;
        int val = (idx < n) ? cnt[idx] : 0;
        int x = val;
        #pragma unroll
        for (int s = 1; s < 64; s <<= 1) {
            int y = __shfl_up(x, s, 64);
            if (lane >= s) x += y;
        }
        if (lane == 63) wsum[wid] = x;
        __syncthreads();
        if (tid == 0) {
            int c = carry_s;
            #pragma unroll
            for (int w = 0; w < 16; w++) { int t = wsum[w]; wsum[w] = c; c += t; }
            carry_s = c;
        }
        __syncthreads();
        int incl = wsum[wid] + x;
        if (idx < n) {
            off[idx + 1] = incl;
            cnt[idx] = incl - val;
        }
        __syncthreads();
    }
}

__global__ __launch_bounds__(256) void fill_kernel(const int* __restrict__ src,
                                                   const int* __restrict__ dst,
                                                   int* __restrict__ cursor,
                                                   int* __restrict__ csr_src, int E) {
    int e = blockIdx.x * 256 + threadIdx.x;
    if (e < E) {
        int p = atomicAdd(&cursor[dst[e]], 1);
        csr_src[p] = src[e];
    }
}

// ---------------------------------------------------------------------------
// Mean aggregation: 4 nodes/block, 1 wave/node, bf16x2/lane, unroll x8.
// ---------------------------------------------------------------------------
__global__ __launch_bounds__(256) void mean2_kernel(const bf16* __restrict__ x, int xstride,
                                                    const int* __restrict__ off,
                                                    const int* __restrict__ csr_src,
                                                    bf16* __restrict__ outp, int ostride) {
    int node = blockIdx.x * 4 + (threadIdx.x >> 6);
    int lane = threadIdx.x & 63;
    int e0 = off[node], e1 = off[node + 1];
    float s0 = 0.f, s1 = 0.f;
    int e = e0;
    for (; e + 7 < e1; e += 8) {
        uint a[8];
        #pragma unroll
        for (int j = 0; j < 8; j++) {
            int sa = csr_src[e + j];
            a[j] = *(const uint*)(x + (size_t)sa * xstride + lane * 2);
        }
        #pragma unroll
        for (int j = 0; j < 8; j++) {
            union { uint i; float f; } t;
            t.i = a[j] << 16; s0 += t.f;
            t.i = a[j] & 0xffff0000u; s1 += t.f;
        }
    }
    for (; e < e1; e++) {
        int sa = csr_src[e];
        uint a = *(const uint*)(x + (size_t)sa * xstride + lane * 2);
        union { uint i; float f; } t;
        t.i = a << 16; s0 += t.f; t.i = a & 0xffff0000u; s1 += t.f;
    }
    int deg = e1 - e0;
    float inv = (deg > 0) ? 1.f / (float)deg : 0.f;
    uint r = ((uint)f2bfr(s1 * inv) << 16) | (uint)f2bfr(s0 * inv);
    *(uint*)(outp + (size_t)node * ostride + lane * 2) = r;
}

// ---------------------------------------------------------------------------
// bf16 MFMA GEMM: C[M,N] = A[M,K] @ Wt[N,K]^T, fused epilogue. BK=64.
// XOR-swizzled LDS staging (R12-proven, conflict-free) + NEW LDS-bounce
// vectorized epilogue: acc tile staged in LDS (ushort, row stride 136 for
// alignment + bank spread), then written out 16B/lane, 4 full 256B row
// segments per store instruction (was: 64 scalar 2B stores/thread).
// MODE 2: relu(+bias), bf16.
// MODE 5: +bias; store f16 for gn<512 (q,k), bf16 else (v,skip)  [qkvs]
// MODE 4: sigmoid(+bias) then grouped max-pool (sorted batch) -> ~1 atomic/col.
// ---------------------------------------------------------------------------
template <int MODE, int TM>
__global__ __launch_bounds__(256, (TM == 128) ? 3 : 4)
void gemm_kernel(const bf16* __restrict__ A,
                 const bf16* __restrict__ Wt,
                 const float* __restrict__ bias,
                 void* __restrict__ Cv,
                 int M, int K, int N, int cstride,
                 const int* __restrict__ batch,
                 float* __restrict__ pool_out) {
    constexpr int NT = (TM == 128) ? 4 : 2;   // n-tiles per wave
    constexpr int CSTR = 136;                 // ctile row stride (shorts): 272B, 16B-aligned
    union SMem {
        struct { short As[TM * 64]; short Bs[128 * 64]; } st;
        ushort ctile[TM * CSTR];
    };
    __shared__ SMem sm;
    __shared__ int bat[TM];
    int t = threadIdx.x;
    int lane = t & 63;
    int wave = t >> 6;
    int wm = (TM == 128) ? (wave >> 1) * 64 : 0;
    int wn = (TM == 128) ? (wave & 1) * 64 : wave * 32;
    int bm = blockIdx.y * TM, bn = blockIdx.x * 128;
    int quad = lane >> 4, l16 = lane & 15;
    int srow = t >> 3;                       // 32 staging rows per round
    int sc8  = t & 7;                        // LDS chunk slot (16B units)
    int scol = sc8 * 8;                      // LDS offset (shorts)
    int gcol = (sc8 ^ (srow & 7)) * 8;       // swizzled global chunk offset
    int sw   = l16 & 7;                      // read-side swizzle key

    if (MODE == 4 && t < TM) bat[t] = batch[min(bm + t, M - 1)];

    f32x4 acc[4][NT];
    f32x4 zero = {0.f, 0.f, 0.f, 0.f};
    #pragma unroll
    for (int i = 0; i < 4; i++)
        #pragma unroll
        for (int j = 0; j < NT; j++) acc[i][j] = zero;

    for (int kk = 0; kk < K; kk += 64) {
        #pragma unroll
        for (int r = 0; r < TM / 32; r++) {
            int row = r * 32 + srow;         // (row&7)==(srow&7): gcol valid
            int gm = bm + row; gm = (gm < M) ? gm : (M - 1);
            load_lds16(A + (size_t)gm * K + kk + gcol, &sm.st.As[row * 64 + scol]);
        }
        #pragma unroll
        for (int r = 0; r < 4; r++) {
            int row = r * 32 + srow;
            load_lds16(Wt + (size_t)(bn + row) * K + kk + gcol, &sm.st.Bs[row * 64 + scol]);
        }
        __syncthreads();
        #pragma unroll
        for (int ks = 0; ks < 2; ks++) {
            short8 af[4], bfr[NT];
            #pragma unroll
            for (int i = 0; i < 4; i++)
                af[i] = *(const short8*)&sm.st.As[(wm + i * 16 + l16) * 64 + ((ks * 4 + quad) ^ sw) * 8];
            #pragma unroll
            for (int j = 0; j < NT; j++)
                bfr[j] = *(const short8*)&sm.st.Bs[(wn + j * 16 + l16) * 64 + ((ks * 4 + quad) ^ sw) * 8];
            #pragma unroll
            for (int i = 0; i < 4; i++)
                #pragma unroll
                for (int j = 0; j < NT; j++)
                    acc[i][j] = __builtin_amdgcn_mfma_f32_16x16x32_bf16(af[i], bfr[j], acc[i][j], 0, 0, 0);
        }
        __syncthreads();
    }
    // after the loop's trailing barrier, As/Bs are dead -> ctile may alias

    if (MODE == 4) {
        int g0 = bat[0], gL = bat[TM - 1];
        #pragma unroll
        for (int j = 0; j < NT; j++) {
            int gn = bn + wn + j * 16 + l16;
            float m0 = 0.f, m1 = 0.f;
            #pragma unroll
            for (int i = 0; i < 4; i++) {
                #pragma unroll
                for (int r = 0; r < 4; r++) {
                    int row = i * 16 + quad * 4 + r;
                    int gm = bm + row;
                    if (gm >= M) continue;
                    float v = acc[i][j][r] + bias[gn];
                    v = 1.f / (1.f + expf(-v));
                    int g = bat[row];
                    if (g == g0) m0 = fmaxf(m0, v);
                    else if (g == gL) m1 = fmaxf(m1, v);
                    else atomicMax((int*)&pool_out[g * 128 + gn], __float_as_int(v));
                }
            }
            m0 = fmaxf(m0, __shfl_xor(m0, 16));
            m0 = fmaxf(m0, __shfl_xor(m0, 32));
            m1 = fmaxf(m1, __shfl_xor(m1, 16));
            m1 = fmaxf(m1, __shfl_xor(m1, 32));
            if (quad == 0) {
                atomicMax((int*)&pool_out[g0 * 128 + gn], __float_as_int(m0));
                if (gL != g0)
                    atomicMax((int*)&pool_out[gL * 128 + gn], __float_as_int(m1));
            }
        }
        return;
    }

    // ---- stage converted tile in LDS (C/D layout col=lane&15, row=quad*4+reg) ----
    #pragma unroll
    for (int i = 0; i < 4; i++) {
        int row0 = wm + i * 16 + quad * 4;
        #pragma unroll
        for (int j = 0; j < NT; j++) {
            int col = wn + j * 16 + l16;
            int gn = bn + col;
            #pragma unroll
            for (int r = 0; r < 4; r++) {
                float v = acc[i][j][r] + bias[gn];
                if (MODE == 2) v = fmaxf(v, 0.f);
                ushort st;
                if (MODE == 5 && gn < 512) {
                    __half hh = __float2half(v);
                    st = *(ushort*)&hh;
                } else {
                    st = f2bfr(v);
                }
                sm.ctile[(row0 + r) * CSTR + col] = st;
            }
        }
    }
    __syncthreads();

    // ---- coalesced write-out: 4 full 256B row segments per instruction ----
    int orow = t >> 4;          // 0..15
    int ocol = (t & 15) * 8;    // 16B chunk within row
    #pragma unroll
    for (int rb = 0; rb < TM / 16; rb++) {
        int row = rb * 16 + orow;
        int gm = bm + row;
        if (gm < M) {
            short8 val = *(const short8*)&sm.ctile[row * CSTR + ocol];
            *(short8*)((ushort*)Cv + (size_t)gm * cstride + bn + ocol) = val;
        }
    }
}

template <int MODE, int TM>
static void launch_gemm(const bf16* A, const bf16* Wt, const float* bias, void* C,
                        int M, int K, int N, int cstride, hipStream_t st,
                        const int* batch = nullptr, float* pool_out = nullptr) {
    dim3 grid(N / 128, (M + TM - 1) / TM);
    hipLaunchKernelGGL((gemm_kernel<MODE, TM>), grid, dim3(256), 0, st,
                       A, Wt, bias, C, M, K, N, cstride, batch, pool_out);
}

// ---------------------------------------------------------------------------
// TransformerConv attention v5 (R8/R10-proven): no-max softmax, pipelined
// chunks, f16 q/k dot via v_dot2_f32_f16, paired (uint) v loads.
// qkvs row stride 1024: [q f16(256) k f16(256) v bf16(256) skip bf16(256)].
// ---------------------------------------------------------------------------
__global__ __launch_bounds__(256) void attn5_kernel(const bf16* __restrict__ qkvs,
                                                    const int* __restrict__ off,
                                                    const int* __restrict__ csr_src,
                                                    bf16* __restrict__ out, int ostride) {
    __shared__ float pp[2][CH][9];
    __shared__ int srcs[2][CH];
    int i = blockIdx.x;
    int tid = threadIdx.x;
    int ea = tid >> 4, ha = (tid >> 1) & 7, half = tid & 1;   // phase A
    int hc = tid >> 5, dp = (tid >> 1) & 15, epar = tid & 1;  // phase C

    // q fragment: 16 dims as 8 half2 pairs
    uint q2[8];
    {
        const uint4v* qp = (const uint4v*)(qkvs + (size_t)i * 1024 + ha * 32 + half * 16);
        uint4v a = qp[0], b = qp[1];
        q2[0] = a.x; q2[1] = a.y; q2[2] = a.z; q2[3] = a.w;
        q2[4] = b.x; q2[5] = b.y; q2[6] = b.z; q2[7] = b.w;
    }

    int e0 = off[i], e1 = off[i + 1];
    float l = 0.f, acc0 = 0.f, acc1 = 0.f;
    int vcol = 512 + hc * 32 + dp * 2;
    if (e0 < e1) {
        if (tid < CH) srcs[0][tid] = csr_src[min(e0 + tid, e1 - 1)];
        __syncthreads();
        int buf = 0;
        for (int base = e0; base < e1; base += CH, buf ^= 1) {
            int cnt = min(CH, e1 - base);
            // ---- issue paired v loads (8 uints cover my 2 dims x 16 edges) ----
            uint vv[8];
            #pragma unroll
            for (int j = 0; j < 8; j++) {
                int e = epar + j * 2;
                vv[j] = *(const uint*)(qkvs + (size_t)srcs[buf][e] * 1024 + vcol);
            }
            // ---- A: k load + fdot2 chain + exp (no max) ----
            int s = srcs[buf][ea];
            const uint4v* kp = (const uint4v*)(qkvs + (size_t)s * 1024 + 256 + ha * 32 + half * 16);
            uint4v ka = kp[0], kb = kp[1];
            // prefetch next chunk's srcs (16 threads, clamped)
            if (tid < CH) srcs[buf ^ 1][tid] = csr_src[min(base + CH + tid, e1 - 1)];
            float d = 0.f;
            d = dot2acc(q2[0], ka.x, d); d = dot2acc(q2[1], ka.y, d);
            d = dot2acc(q2[2], ka.z, d); d = dot2acc(q2[3], ka.w, d);
            d = dot2acc(q2[4], kb.x, d); d = dot2acc(q2[5], kb.y, d);
            d = dot2acc(q2[6], kb.z, d); d = dot2acc(q2[7], kb.w, d);
            d += __shfl_xor(d, 1);
            float p = (ea < cnt) ? __expf(d * 0.17677669529663687f) : 0.f;
            if (half == 0) pp[buf][ea][ha] = p;
            __syncthreads();
            // ---- C: weighted V (my parity's 8 edges), l per-thread ----
            #pragma unroll
            for (int j = 0; j < 8; j++) {
                int e = epar + j * 2;
                float pj = pp[buf][e][hc];
                l += pj;
                union { uint i; float f; } lo, hi;
                lo.i = vv[j] << 16; hi.i = vv[j] & 0xffff0000u;
                acc0 += pj * lo.f;
                acc1 += pj * hi.f;
            }
        }
    }
    // combine edge parities (thread pair tid, tid^1)
    acc0 += __shfl_xor(acc0, 1);
    acc1 += __shfl_xor(acc1, 1);
    l    += __shfl_xor(l, 1);
    float inv = (l > 0.f) ? 1.f / l : 0.f;
    float r0 = acc0 * inv, r1 = acc1 * inv;
    if (epar == 0) {
        uint su = *(const uint*)(qkvs + (size_t)i * 1024 + 768 + hc * 32 + dp * 2);
        union { uint i; float f; } lo, hi;
        lo.i = su << 16; hi.i = su & 0xffff0000u;
        float v0 = fmaxf(r0 + lo.f, 0.f);
        float v1 = fmaxf(r1 + hi.f, 0.f);
        uint packed = ((uint)f2bfr(v1) << 16) | (uint)f2bfr(v0);
        *(uint*)(out + (size_t)i * ostride + hc * 32 + dp * 2) = packed;
    }
}

// ---------------------------------------------------------------------------
extern "C" void kernel_launch(void* const* d_in, const int* in_sizes, int n_in,
                              void* d_out, int out_size, void* d_ws, size_t ws_size,
                              hipStream_t stream) {
    const float* x      = (const float*)d_in[0];
    const int*   ei     = (const int*)d_in[1];
    const int*   batch  = (const int*)d_in[2];
    const float* s1_wl  = (const float*)d_in[3];
    const float* s1_bl  = (const float*)d_in[4];
    const float* s1_wr  = (const float*)d_in[5];
    const float* s2_wl  = (const float*)d_in[6];
    const float* s2_bl  = (const float*)d_in[7];
    const float* s2_wr  = (const float*)d_in[8];
    const float* t1_wq  = (const float*)d_in[9];
    const float* t1_bq  = (const float*)d_in[10];
    const float* t1_wk  = (const float*)d_in[11];
    const float* t1_bk  = (const float*)d_in[12];
    const float* t1_wv  = (const float*)d_in[13];
    const float* t1_bv  = (const float*)d_in[14];
    const float* t1_ws  = (const float*)d_in[15];
    const float* t1_bs  = (const float*)d_in[16];
    const float* t2_wq  = (const float*)d_in[17];
    const float* t2_bq  = (const float*)d_in[18];
    const float* t2_wk  = (const float*)d_in[19];
    const float* t2_bk  = (const float*)d_in[20];
    const float* t2_wv  = (const float*)d_in[21];
    const float* t2_bv  = (const float*)d_in[22];
    const float* t2_wsk = (const float*)d_in[23];
    const float* t2_bs  = (const float*)d_in[24];
    const float* p1_w   = (const float*)d_in[25];
    const float* p1_b   = (const float*)d_in[26];
    const float* p2_w   = (const float*)d_in[27];
    const float* p2_b   = (const float*)d_in[28];
    float* out = (float*)d_out;

    // ---- workspace layout ----
    char* ws = (char*)d_ws;
    size_t o = 0;
    auto alloc = [&](size_t bytes) { char* p = ws + o; o += (bytes + 255) & ~(size_t)255; return p; };
    int* off     = (int*)alloc(sizeof(int) * (NN + 1));
    int* cursor  = (int*)alloc(sizeof(int) * NN);
    int* csr_src = (int*)alloc(sizeof(int) * EE);
    bf16* w1cat = (bf16*)alloc(2 * 128 * 256);
    bf16* w2cat = (bf16*)alloc(2 * 256 * 256);
    bf16* qw1   = (bf16*)alloc(2 * 1024 * 256);
    bf16* qw2   = (bf16*)alloc(2 * 1024 * 256);
    bf16* p1t   = (bf16*)alloc(2 * 512 * 256);
    bf16* p2t   = (bf16*)alloc(2 * 128 * 512);
    float* qb1  = (float*)alloc(4 * 1024);
    float* qb2  = (float*)alloc(4 * 1024);
    bf16* xm1   = (bf16*)alloc(2 * (size_t)NN * 256);   // [x | mean(x)]; later h2/h4
    bf16* xm2   = (bf16*)alloc(2 * (size_t)NN * 256);   // [h1 | mean(h1)]
    bf16* t1b   = (bf16*)alloc(2 * (size_t)NN * 512);   // t1 (stride 256); later p1o
    bf16* Q     = (bf16*)alloc(2 * (size_t)NN * 1024);  // qkvs
    bf16* h2   = xm1;
    bf16* t1   = t1b;
    bf16* h4   = xm1;
    bf16* p1o  = t1b;

    const int* src = ei;
    const int* dst = ei + EE;

    // ---- memset (cursor for CSR count; pool-out zeroed inside prep) ----
    hipMemsetAsync(cursor, 0, sizeof(int) * NN, stream);

    // ---- fused prep: conv x + tiled transpose + biases + out-zero + count ----
    prep_kernel<<<PREP_COUNT, 256, 0, stream>>>(
        x, xm1,
        s1_wr, s1_wl, s2_wr, s2_wl,
        t1_wq, t1_wk, t1_wv, t1_ws,
        t2_wq, t2_wk, t2_wv, t2_wsk,
        p1_w, p2_w,
        w1cat, w2cat, qw1, qw2, p1t, p2t,
        t1_bq, t1_bk, t1_bv, t1_bs,
        t2_bq, t2_bk, t2_bv, t2_bs,
        qb1, qb2,
        out,
        dst, cursor);

    // ---- CSR scan + fill ----
    scan_kernel<<<1, 1024, 0, stream>>>(cursor, off, NN);
    fill_kernel<<<(EE + 255) / 256, 256, 0, stream>>>(src, dst, cursor, csr_src, EE);

    // ---- SAGE 1: h1 = relu([x|mean(x)] @ w1cat + bl) -> xm2 first half ----
    mean2_kernel<<<NN / 4, 256, 0, stream>>>(xm1, 256, off, csr_src, xm1 + 128, 256);
    launch_gemm<2, 64>(xm1, w1cat, s1_bl, xm2, NN, 256, 128, 256, stream);

    // ---- SAGE 2: h2 = relu([h1|mean(h1)] @ w2cat + bl) ----
    mean2_kernel<<<NN / 4, 256, 0, stream>>>(xm2, 256, off, csr_src, xm2 + 128, 256);
    launch_gemm<2, 64>(xm2, w2cat, s2_bl, h2, NN, 256, 256, 256, stream);

    // ---- TransformerConv 1 (qkvs GEMM stores q,k f16 / v,skip bf16) ----
    launch_gemm<5, 128>(h2, qw1, qb1, Q, NN, 256, 1024, 1024, stream);
    attn5_kernel<<<NN, 256, 0, stream>>>(Q, off, csr_src, t1, 256);

    // ---- TransformerConv 2 ----
    launch_gemm<5, 128>(t1, qw2, qb2, Q, NN, 256, 1024, 1024, stream);
    attn5_kernel<<<NN, 256, 0, stream>>>(Q, off, csr_src, h4, 256);

    // ---- proj MLP (p2 fuses sigmoid + grouped max pool) ----
    launch_gemm<2, 128>(h4, p1t, p1_b, p1o, NN, 256, 512, 512, stream);
    launch_gemm<4, 64>(p1o, p2t, p2_b, nullptr, NN, 512, 128, 128, stream, batch, out);
}

// Round 14
// 374.071 us; speedup vs baseline: 1.2551x; 1.0169x over previous
//
#include <hip/hip_runtime.h>
#include <hip/hip_bf16.h>
#include <hip/hip_fp16.h>
#include <math.h>

#define NN 20000
#define EE 320000
#define GG 64
#define CH 16   // attention chunk size (edges)

typedef __hip_bfloat16 bf16;
typedef __attribute__((ext_vector_type(8))) short short8;
typedef __attribute__((ext_vector_type(4))) float f32x4;
typedef __attribute__((ext_vector_type(4))) unsigned int uint4v;
typedef __attribute__((ext_vector_type(2))) unsigned int uint2v;
typedef __attribute__((ext_vector_type(2))) _Float16 half2v;
typedef unsigned int uint;
typedef unsigned short ushort;

__device__ __forceinline__ float bfr2f(ushort u) {
    union { uint i; float f; } c; c.i = ((uint)u) << 16; return c.f;
}
__device__ __forceinline__ ushort f2bfr(float f) {
    bf16 h = __float2bfloat16(f);
    return *(ushort*)&h;
}

// fp16-pair dot with f32 accumulate: c + a.x*b.x + a.y*b.y
__device__ __forceinline__ float dot2acc(uint a, uint b, float c) {
#if __has_builtin(__builtin_amdgcn_fdot2)
    return __builtin_amdgcn_fdot2(__builtin_bit_cast(half2v, a),
                                  __builtin_bit_cast(half2v, b), c, false);
#else
    half2v ha = __builtin_bit_cast(half2v, a);
    half2v hb = __builtin_bit_cast(half2v, b);
    return c + (float)ha.x * (float)hb.x + (float)ha.y * (float)hb.y;
#endif
}

// ---------------------------------------------------------------------------
// async global->LDS 16B copy
// ---------------------------------------------------------------------------
__device__ __forceinline__ void load_lds16(const void* g, void* l) {
    __builtin_amdgcn_global_load_lds(
        (const __attribute__((address_space(1))) unsigned int*)g,
        (__attribute__((address_space(3))) unsigned int*)l, 16, 0, 0);
}

// ---------------------------------------------------------------------------
// fused prep: x->bf16 (vectorized x8, strided), LDS-tiled weight transposes,
// biases, pool-output zeroing, CSR count
// ---------------------------------------------------------------------------
#define PREP_CONV  1250                  // NN*128/8/256 blocks: x convert (x8 vec)
#define PREP_TP    (PREP_CONV + 800)     // 800 32x32 transpose tiles
#define PREP_BIAS  (PREP_TP + 8)
#define PREP_OUTZ  (PREP_BIAS + 32)      // zero GG*128 pool output
#define PREP_COUNT (PREP_OUTZ + 1250)

__global__ __launch_bounds__(256) void prep_kernel(
    const float* x, bf16* xm1,
    const float* s1_wr, const float* s1_wl, const float* s2_wr, const float* s2_wl,
    const float* t1_wq, const float* t1_wk, const float* t1_wv, const float* t1_ws,
    const float* t2_wq, const float* t2_wk, const float* t2_wv, const float* t2_ws,
    const float* p1_w, const float* p2_w,
    bf16* w1cat, bf16* w2cat, bf16* qw1, bf16* qw2, bf16* p1t, bf16* p2t,
    const float* b1q, const float* b1k, const float* b1v, const float* b1s,
    const float* b2q, const float* b2k, const float* b2v, const float* b2s,
    float* qb1, float* qb2,
    float* pool_out,
    const int* dst, int* cnt) {
    __shared__ float tile[32][33];
    int bid = blockIdx.x;
    int tid = threadIdx.x;
    if (bid < PREP_CONV) {
        int g = bid * 256 + tid;            // < NN*128/8 = 320000
        int row = g >> 4;
        int col = (g & 15) * 8;
        f32x4 a = *(const f32x4*)(x + (size_t)row * 128 + col);
        f32x4 b = *(const f32x4*)(x + (size_t)row * 128 + col + 4);
        short8 v;
        v[0] = (short)f2bfr(a.x); v[1] = (short)f2bfr(a.y);
        v[2] = (short)f2bfr(a.z); v[3] = (short)f2bfr(a.w);
        v[4] = (short)f2bfr(b.x); v[5] = (short)f2bfr(b.y);
        v[6] = (short)f2bfr(b.z); v[7] = (short)f2bfr(b.w);
        *(short8*)(xm1 + (size_t)row * 256 + col) = v;
    } else if (bid < PREP_TP) {
        // ---- LDS-tiled transpose: Wt[n][KOFF+k] = bf16(W[k][n]) ----
        int tb = bid - PREP_CONV;   // 0..799
        const float* W; bf16* Wt; int KW, NW, KT, KO, lt;
        const float* t1w[4] = {t1_wq, t1_wk, t1_wv, t1_ws};
        const float* t2w[4] = {t2_wq, t2_wk, t2_wv, t2_ws};
        if (tb < 16)       { W = s1_wr; Wt = w1cat; KW = 128; NW = 128; KT = 256; KO = 0;   lt = tb; }
        else if (tb < 32)  { W = s1_wl; Wt = w1cat; KW = 128; NW = 128; KT = 256; KO = 128; lt = tb - 16; }
        else if (tb < 64)  { W = s2_wr; Wt = w2cat; KW = 128; NW = 256; KT = 256; KO = 0;   lt = tb - 32; }
        else if (tb < 96)  { W = s2_wl; Wt = w2cat; KW = 128; NW = 256; KT = 256; KO = 128; lt = tb - 64; }
        else if (tb < 352) { int m = (tb - 96) >> 6;  W = t1w[m]; Wt = qw1 + m * 65536; KW = 256; NW = 256; KT = 256; KO = 0; lt = (tb - 96) & 63; }
        else if (tb < 608) { int m = (tb - 352) >> 6; W = t2w[m]; Wt = qw2 + m * 65536; KW = 256; NW = 256; KT = 256; KO = 0; lt = (tb - 352) & 63; }
        else if (tb < 736) { W = p1_w; Wt = p1t; KW = 256; NW = 512; KT = 256; KO = 0; lt = tb - 608; }
        else               { W = p2_w; Wt = p2t; KW = 512; NW = 128; KT = 512; KO = 0; lt = tb - 736; }
        int ntiles_n = NW >> 5;
        int k0 = (lt / ntiles_n) * 32;
        int n0 = (lt % ntiles_n) * 32;
        int tx = tid & 31, ty = tid >> 5;   // ty 0..7
        #pragma unroll
        for (int r = 0; r < 4; r++)
            tile[ty + 8 * r][tx] = W[(size_t)(k0 + ty + 8 * r) * NW + n0 + tx];
        __syncthreads();
        #pragma unroll
        for (int r = 0; r < 4; r++)
            Wt[(size_t)(n0 + ty + 8 * r) * KT + KO + k0 + tx] =
                __float2bfloat16(tile[tx][ty + 8 * r]);
    } else if (bid < PREP_BIAS) {
        int i = (bid - PREP_TP) * 256 + tid;
        if (i < 2048) {
            float* d = (i < 1024) ? qb1 : qb2;
            int j = i & 1023;
            const float* s;
            if (i < 1024) s = (j < 256) ? b1q : (j < 512) ? b1k : (j < 768) ? b1v : b1s;
            else          s = (j < 256) ? b2q : (j < 512) ? b2k : (j < 768) ? b2v : b2s;
            d[j] = s[j & 255];
        }
    } else if (bid < PREP_OUTZ) {
        int i = (bid - PREP_BIAS) * 256 + tid;
        if (i < GG * 128) pool_out[i] = 0.f;
    } else {
        int e = (bid - PREP_OUTZ) * 256 + tid;
        if (e < EE) atomicAdd(&cnt[dst[e]], 1);
    }
}

// ---------------------------------------------------------------------------
// scan: shfl-based wave scan. cnt -> off (excl), cursor.
// ---------------------------------------------------------------------------
__global__ __launch_bounds__(1024) void scan_kernel(int* __restrict__ cnt,
                                                    int* __restrict__ off, int n) {
    __shared__ int wsum[16];
    __shared__ int carry_s;
    int tid = threadIdx.x;
    int lane = tid & 63, wid = tid >> 6;
    if (tid == 0) { carry_s = 0; off[0] = 0; }
    __syncthreads();
    for (int base = 0; base < n; base += 1024) {
        int idx = base + tid;
        int val = (idx < n) ? cnt[idx] : 0;
        int x = val;
        #pragma unroll
        for (int s = 1; s < 64; s <<= 1) {
            int y = __shfl_up(x, s, 64);
            if (lane >= s) x += y;
        }
        if (lane == 63) wsum[wid] = x;
        __syncthreads();
        if (tid == 0) {
            int c = carry_s;
            #pragma unroll
            for (int w = 0; w < 16; w++) { int t = wsum[w]; wsum[w] = c; c += t; }
            carry_s = c;
        }
        __syncthreads();
        int incl = wsum[wid] + x;
        if (idx < n) {
            off[idx + 1] = incl;
            cnt[idx] = incl - val;
        }
        __syncthreads();
    }
}

__global__ __launch_bounds__(256) void fill_kernel(const int* __restrict__ src,
                                                   const int* __restrict__ dst,
                                                   int* __restrict__ cursor,
                                                   int* __restrict__ csr_src, int E) {
    int e = blockIdx.x * 256 + threadIdx.x;
    if (e < E) {
        int p = atomicAdd(&cursor[dst[e]], 1);
        csr_src[p] = src[e];
    }
}

// ---------------------------------------------------------------------------
// Mean aggregation v2: 4 nodes/block, 1 wave/node.
// lane = (edge-parity el=l>>5, dim-quad dp=l&31): 8B uint2 loads, 2 edges per
// lane-iteration, masked (not clamped) tail; parities combined via shfl(32).
// ---------------------------------------------------------------------------
__global__ __launch_bounds__(256) void mean2_kernel(const bf16* __restrict__ x, int xstride,
                                                    const int* __restrict__ off,
                                                    const int* __restrict__ csr_src,
                                                    bf16* __restrict__ outp, int ostride) {
    int node = blockIdx.x * 4 + (threadIdx.x >> 6);
    int l = threadIdx.x & 63;
    int el = l >> 5;          // edge parity within pair
    int dp = l & 31;          // dim quad: cols [dp*4, dp*4+4)
    int e0 = off[node], e1 = off[node + 1];
    float s0 = 0.f, s1 = 0.f, s2 = 0.f, s3 = 0.f;
    for (int e = e0; e < e1; e += 8) {
        uint2v a[4];
        #pragma unroll
        for (int j = 0; j < 4; j++) {
            int ee = e + j * 2 + el;
            int sa = csr_src[min(ee, e1 - 1)];
            uint2v v = *(const uint2v*)(x + (size_t)sa * xstride + dp * 4);
            uint m = (ee < e1) ? 0xffffffffu : 0u;
            a[j].x = v.x & m;
            a[j].y = v.y & m;
        }
        #pragma unroll
        for (int j = 0; j < 4; j++) {
            union { uint i; float f; } t;
            t.i = a[j].x << 16;         s0 += t.f;
            t.i = a[j].x & 0xffff0000u; s1 += t.f;
            t.i = a[j].y << 16;         s2 += t.f;
            t.i = a[j].y & 0xffff0000u; s3 += t.f;
        }
    }
    s0 += __shfl_xor(s0, 32);
    s1 += __shfl_xor(s1, 32);
    s2 += __shfl_xor(s2, 32);
    s3 += __shfl_xor(s3, 32);
    if (el == 0) {
        int deg = e1 - e0;
        float inv = (deg > 0) ? 1.f / (float)deg : 0.f;
        uint2v r;
        r.x = ((uint)f2bfr(s1 * inv) << 16) | (uint)f2bfr(s0 * inv);
        r.y = ((uint)f2bfr(s3 * inv) << 16) | (uint)f2bfr(s2 * inv);
        *(uint2v*)(outp + (size_t)node * ostride + dp * 4) = r;
    }
}

// ---------------------------------------------------------------------------
// bf16 MFMA GEMM: C[M,N] = A[M,K] @ Wt[N,K]^T, fused epilogue. BK=64.
// XOR-swizzled LDS staging (conflict-free) + LDS-bounce vectorized epilogue.
// Occupancy: TM=128 -> 4 blocks/CU (LDS 34KB), TM=64 -> 5 blocks/CU (24KB).
// MODE 2: relu(+bias), bf16.
// MODE 5: +bias; store f16 for gn<512 (q,k), bf16 else (v,skip)  [qkvs]
// MODE 4: sigmoid(+bias) then grouped max-pool (sorted batch) -> ~1 atomic/col.
// ---------------------------------------------------------------------------
template <int MODE, int TM>
__global__ __launch_bounds__(256, (TM == 128) ? 4 : 5)
void gemm_kernel(const bf16* __restrict__ A,
                 const bf16* __restrict__ Wt,
                 const float* __restrict__ bias,
                 void* __restrict__ Cv,
                 int M, int K, int N, int cstride,
                 const int* __restrict__ batch,
                 float* __restrict__ pool_out) {
    constexpr int NT = (TM == 128) ? 4 : 2;   // n-tiles per wave
    constexpr int CSTR = 136;                 // ctile row stride (shorts): 272B, 16B-aligned
    union SMem {
        struct { short As[TM * 64]; short Bs[128 * 64]; } st;
        ushort ctile[TM * CSTR];
    };
    __shared__ SMem sm;
    __shared__ int bat[TM];
    int t = threadIdx.x;
    int lane = t & 63;
    int wave = t >> 6;
    int wm = (TM == 128) ? (wave >> 1) * 64 : 0;
    int wn = (TM == 128) ? (wave & 1) * 64 : wave * 32;
    int bm = blockIdx.y * TM, bn = blockIdx.x * 128;
    int quad = lane >> 4, l16 = lane & 15;
    int srow = t >> 3;                       // 32 staging rows per round
    int sc8  = t & 7;                        // LDS chunk slot (16B units)
    int scol = sc8 * 8;                      // LDS offset (shorts)
    int gcol = (sc8 ^ (srow & 7)) * 8;       // swizzled global chunk offset
    int sw   = l16 & 7;                      // read-side swizzle key

    if (MODE == 4 && t < TM) bat[t] = batch[min(bm + t, M - 1)];

    f32x4 acc[4][NT];
    f32x4 zero = {0.f, 0.f, 0.f, 0.f};
    #pragma unroll
    for (int i = 0; i < 4; i++)
        #pragma unroll
        for (int j = 0; j < NT; j++) acc[i][j] = zero;

    for (int kk = 0; kk < K; kk += 64) {
        #pragma unroll
        for (int r = 0; r < TM / 32; r++) {
            int row = r * 32 + srow;         // (row&7)==(srow&7): gcol valid
            int gm = bm + row; gm = (gm < M) ? gm : (M - 1);
            load_lds16(A + (size_t)gm * K + kk + gcol, &sm.st.As[row * 64 + scol]);
        }
        #pragma unroll
        for (int r = 0; r < 4; r++) {
            int row = r * 32 + srow;
            load_lds16(Wt + (size_t)(bn + row) * K + kk + gcol, &sm.st.Bs[row * 64 + scol]);
        }
        __syncthreads();
        #pragma unroll
        for (int ks = 0; ks < 2; ks++) {
            short8 af[4], bfr[NT];
            #pragma unroll
            for (int i = 0; i < 4; i++)
                af[i] = *(const short8*)&sm.st.As[(wm + i * 16 + l16) * 64 + ((ks * 4 + quad) ^ sw) * 8];
            #pragma unroll
            for (int j = 0; j < NT; j++)
                bfr[j] = *(const short8*)&sm.st.Bs[(wn + j * 16 + l16) * 64 + ((ks * 4 + quad) ^ sw) * 8];
            #pragma unroll
            for (int i = 0; i < 4; i++)
                #pragma unroll
                for (int j = 0; j < NT; j++)
                    acc[i][j] = __builtin_amdgcn_mfma_f32_16x16x32_bf16(af[i], bfr[j], acc[i][j], 0, 0, 0);
        }
        __syncthreads();
    }
    // after the loop's trailing barrier, As/Bs are dead -> ctile may alias

    if (MODE == 4) {
        int g0 = bat[0], gL = bat[TM - 1];
        #pragma unroll
        for (int j = 0; j < NT; j++) {
            int gn = bn + wn + j * 16 + l16;
            float m0 = 0.f, m1 = 0.f;
            #pragma unroll
            for (int i = 0; i < 4; i++) {
                #pragma unroll
                for (int r = 0; r < 4; r++) {
                    int row = i * 16 + quad * 4 + r;
                    int gm = bm + row;
                    if (gm >= M) continue;
                    float v = acc[i][j][r] + bias[gn];
                    v = 1.f / (1.f + expf(-v));
                    int g = bat[row];
                    if (g == g0) m0 = fmaxf(m0, v);
                    else if (g == gL) m1 = fmaxf(m1, v);
                    else atomicMax((int*)&pool_out[g * 128 + gn], __float_as_int(v));
                }
            }
            m0 = fmaxf(m0, __shfl_xor(m0, 16));
            m0 = fmaxf(m0, __shfl_xor(m0, 32));
            m1 = fmaxf(m1, __shfl_xor(m1, 16));
            m1 = fmaxf(m1, __shfl_xor(m1, 32));
            if (quad == 0) {
                atomicMax((int*)&pool_out[g0 * 128 + gn], __float_as_int(m0));
                if (gL != g0)
                    atomicMax((int*)&pool_out[gL * 128 + gn], __float_as_int(m1));
            }
        }
        return;
    }

    // ---- stage converted tile in LDS (C/D layout col=lane&15, row=quad*4+reg) ----
    #pragma unroll
    for (int i = 0; i < 4; i++) {
        int row0 = wm + i * 16 + quad * 4;
        #pragma unroll
        for (int j = 0; j < NT; j++) {
            int col = wn + j * 16 + l16;
            int gn = bn + col;
            #pragma unroll
            for (int r = 0; r < 4; r++) {
                float v = acc[i][j][r] + bias[gn];
                if (MODE == 2) v = fmaxf(v, 0.f);
                ushort st;
                if (MODE == 5 && gn < 512) {
                    __half hh = __float2half(v);
                    st = *(ushort*)&hh;
                } else {
                    st = f2bfr(v);
                }
                sm.ctile[(row0 + r) * CSTR + col] = st;
            }
        }
    }
    __syncthreads();

    // ---- coalesced write-out: 4 full 256B row segments per instruction ----
    int orow = t >> 4;          // 0..15
    int ocol = (t & 15) * 8;    // 16B chunk within row
    #pragma unroll
    for (int rb = 0; rb < TM / 16; rb++) {
        int row = rb * 16 + orow;
        int gm = bm + row;
        if (gm < M) {
            short8 val = *(const short8*)&sm.ctile[row * CSTR + ocol];
            *(short8*)((ushort*)Cv + (size_t)gm * cstride + bn + ocol) = val;
        }
    }
}

template <int MODE, int TM>
static void launch_gemm(const bf16* A, const bf16* Wt, const float* bias, void* C,
                        int M, int K, int N, int cstride, hipStream_t st,
                        const int* batch = nullptr, float* pool_out = nullptr) {
    dim3 grid(N / 128, (M + TM - 1) / TM);
    hipLaunchKernelGGL((gemm_kernel<MODE, TM>), grid, dim3(256), 0, st,
                       A, Wt, bias, C, M, K, N, cstride, batch, pool_out);
}

// ---------------------------------------------------------------------------
// TransformerConv attention v5 (R8/R10-proven): no-max softmax, pipelined
// chunks, f16 q/k dot via v_dot2_f32_f16, paired (uint) v loads.
// qkvs row stride 1024: [q f16(256) k f16(256) v bf16(256) skip bf16(256)].
// ---------------------------------------------------------------------------
__global__ __launch_bounds__(256) void attn5_kernel(const bf16* __restrict__ qkvs,
                                                    const int* __restrict__ off,
                                                    const int* __restrict__ csr_src,
                                                    bf16* __restrict__ out, int ostride) {
    __shared__ float pp[2][CH][9];
    __shared__ int srcs[2][CH];
    int i = blockIdx.x;
    int tid = threadIdx.x;
    int ea = tid >> 4, ha = (tid >> 1) & 7, half = tid & 1;   // phase A
    int hc = tid >> 5, dp = (tid >> 1) & 15, epar = tid & 1;  // phase C

    // q fragment: 16 dims as 8 half2 pairs
    uint q2[8];
    {
        const uint4v* qp = (const uint4v*)(qkvs + (size_t)i * 1024 + ha * 32 + half * 16);
        uint4v a = qp[0], b = qp[1];
        q2[0] = a.x; q2[1] = a.y; q2[2] = a.z; q2[3] = a.w;
        q2[4] = b.x; q2[5] = b.y; q2[6] = b.z; q2[7] = b.w;
    }

    int e0 = off[i], e1 = off[i + 1];
    float l = 0.f, acc0 = 0.f, acc1 = 0.f;
    int vcol = 512 + hc * 32 + dp * 2;
    if (e0 < e1) {
        if (tid < CH) srcs[0][tid] = csr_src[min(e0 + tid, e1 - 1)];
        __syncthreads();
        int buf = 0;
        for (int base = e0; base < e1; base += CH, buf ^= 1) {
            int cnt = min(CH, e1 - base);
            // ---- issue paired v loads (8 uints cover my 2 dims x 16 edges) ----
            uint vv[8];
            #pragma unroll
            for (int j = 0; j < 8; j++) {
                int e = epar + j * 2;
                vv[j] = *(const uint*)(qkvs + (size_t)srcs[buf][e] * 1024 + vcol);
            }
            // ---- A: k load + fdot2 chain + exp (no max) ----
            int s = srcs[buf][ea];
            const uint4v* kp = (const uint4v*)(qkvs + (size_t)s * 1024 + 256 + ha * 32 + half * 16);
            uint4v ka = kp[0], kb = kp[1];
            // prefetch next chunk's srcs (16 threads, clamped)
            if (tid < CH) srcs[buf ^ 1][tid] = csr_src[min(base + CH + tid, e1 - 1)];
            float d = 0.f;
            d = dot2acc(q2[0], ka.x, d); d = dot2acc(q2[1], ka.y, d);
            d = dot2acc(q2[2], ka.z, d); d = dot2acc(q2[3], ka.w, d);
            d = dot2acc(q2[4], kb.x, d); d = dot2acc(q2[5], kb.y, d);
            d = dot2acc(q2[6], kb.z, d); d = dot2acc(q2[7], kb.w, d);
            d += __shfl_xor(d, 1);
            float p = (ea < cnt) ? __expf(d * 0.17677669529663687f) : 0.f;
            if (half == 0) pp[buf][ea][ha] = p;
            __syncthreads();
            // ---- C: weighted V (my parity's 8 edges), l per-thread ----
            #pragma unroll
            for (int j = 0; j < 8; j++) {
                int e = epar + j * 2;
                float pj = pp[buf][e][hc];
                l += pj;
                union { uint i; float f; } lo, hi;
                lo.i = vv[j] << 16; hi.i = vv[j] & 0xffff0000u;
                acc0 += pj * lo.f;
                acc1 += pj * hi.f;
            }
        }
    }
    // combine edge parities (thread pair tid, tid^1)
    acc0 += __shfl_xor(acc0, 1);
    acc1 += __shfl_xor(acc1, 1);
    l    += __shfl_xor(l, 1);
    float inv = (l > 0.f) ? 1.f / l : 0.f;
    float r0 = acc0 * inv, r1 = acc1 * inv;
    if (epar == 0) {
        uint su = *(const uint*)(qkvs + (size_t)i * 1024 + 768 + hc * 32 + dp * 2);
        union { uint i; float f; } lo, hi;
        lo.i = su << 16; hi.i = su & 0xffff0000u;
        float v0 = fmaxf(r0 + lo.f, 0.f);
        float v1 = fmaxf(r1 + hi.f, 0.f);
        uint packed = ((uint)f2bfr(v1) << 16) | (uint)f2bfr(v0);
        *(uint*)(out + (size_t)i * ostride + hc * 32 + dp * 2) = packed;
    }
}

// ---------------------------------------------------------------------------
extern "C" void kernel_launch(void* const* d_in, const int* in_sizes, int n_in,
                              void* d_out, int out_size, void* d_ws, size_t ws_size,
                              hipStream_t stream) {
    const float* x      = (const float*)d_in[0];
    const int*   ei     = (const int*)d_in[1];
    const int*   batch  = (const int*)d_in[2];
    const float* s1_wl  = (const float*)d_in[3];
    const float* s1_bl  = (const float*)d_in[4];
    const float* s1_wr  = (const float*)d_in[5];
    const float* s2_wl  = (const float*)d_in[6];
    const float* s2_bl  = (const float*)d_in[7];
    const float* s2_wr  = (const float*)d_in[8];
    const float* t1_wq  = (const float*)d_in[9];
    const float* t1_bq  = (const float*)d_in[10];
    const float* t1_wk  = (const float*)d_in[11];
    const float* t1_bk  = (const float*)d_in[12];
    const float* t1_wv  = (const float*)d_in[13];
    const float* t1_bv  = (const float*)d_in[14];
    const float* t1_ws  = (const float*)d_in[15];
    const float* t1_bs  = (const float*)d_in[16];
    const float* t2_wq  = (const float*)d_in[17];
    const float* t2_bq  = (const float*)d_in[18];
    const float* t2_wk  = (const float*)d_in[19];
    const float* t2_bk  = (const float*)d_in[20];
    const float* t2_wv  = (const float*)d_in[21];
    const float* t2_bv  = (const float*)d_in[22];
    const float* t2_wsk = (const float*)d_in[23];
    const float* t2_bs  = (const float*)d_in[24];
    const float* p1_w   = (const float*)d_in[25];
    const float* p1_b   = (const float*)d_in[26];
    const float* p2_w   = (const float*)d_in[27];
    const float* p2_b   = (const float*)d_in[28];
    float* out = (float*)d_out;

    // ---- workspace layout ----
    char* ws = (char*)d_ws;
    size_t o = 0;
    auto alloc = [&](size_t bytes) { char* p = ws + o; o += (bytes + 255) & ~(size_t)255; return p; };
    int* off     = (int*)alloc(sizeof(int) * (NN + 1));
    int* cursor  = (int*)alloc(sizeof(int) * NN);
    int* csr_src = (int*)alloc(sizeof(int) * EE);
    bf16* w1cat = (bf16*)alloc(2 * 128 * 256);
    bf16* w2cat = (bf16*)alloc(2 * 256 * 256);
    bf16* qw1   = (bf16*)alloc(2 * 1024 * 256);
    bf16* qw2   = (bf16*)alloc(2 * 1024 * 256);
    bf16* p1t   = (bf16*)alloc(2 * 512 * 256);
    bf16* p2t   = (bf16*)alloc(2 * 128 * 512);
    float* qb1  = (float*)alloc(4 * 1024);
    float* qb2  = (float*)alloc(4 * 1024);
    bf16* xm1   = (bf16*)alloc(2 * (size_t)NN * 256);   // [x | mean(x)]; later h2/h4
    bf16* xm2   = (bf16*)alloc(2 * (size_t)NN * 256);   // [h1 | mean(h1)]
    bf16* t1b   = (bf16*)alloc(2 * (size_t)NN * 512);   // t1 (stride 256); later p1o
    bf16* Q     = (bf16*)alloc(2 * (size_t)NN * 1024);  // qkvs
    bf16* h2   = xm1;
    bf16* t1   = t1b;
    bf16* h4   = xm1;
    bf16* p1o  = t1b;

    const int* src = ei;
    const int* dst = ei + EE;

    // ---- memset (cursor for CSR count; pool-out zeroed inside prep) ----
    hipMemsetAsync(cursor, 0, sizeof(int) * NN, stream);

    // ---- fused prep: conv x + tiled transpose + biases + out-zero + count ----
    prep_kernel<<<PREP_COUNT, 256, 0, stream>>>(
        x, xm1,
        s1_wr, s1_wl, s2_wr, s2_wl,
        t1_wq, t1_wk, t1_wv, t1_ws,
        t2_wq, t2_wk, t2_wv, t2_wsk,
        p1_w, p2_w,
        w1cat, w2cat, qw1, qw2, p1t, p2t,
        t1_bq, t1_bk, t1_bv, t1_bs,
        t2_bq, t2_bk, t2_bv, t2_bs,
        qb1, qb2,
        out,
        dst, cursor);

    // ---- CSR scan + fill ----
    scan_kernel<<<1, 1024, 0, stream>>>(cursor, off, NN);
    fill_kernel<<<(EE + 255) / 256, 256, 0, stream>>>(src, dst, cursor, csr_src, EE);

    // ---- SAGE 1: h1 = relu([x|mean(x)] @ w1cat + bl) -> xm2 first half ----
    mean2_kernel<<<NN / 4, 256, 0, stream>>>(xm1, 256, off, csr_src, xm1 + 128, 256);
    launch_gemm<2, 64>(xm1, w1cat, s1_bl, xm2, NN, 256, 128, 256, stream);

    // ---- SAGE 2: h2 = relu([h1|mean(h1)] @ w2cat + bl) ----
    mean2_kernel<<<NN / 4, 256, 0, stream>>>(xm2, 256, off, csr_src, xm2 + 128, 256);
    launch_gemm<2, 64>(xm2, w2cat, s2_bl, h2, NN, 256, 256, 256, stream);

    // ---- TransformerConv 1 (qkvs GEMM stores q,k f16 / v,skip bf16) ----
    launch_gemm<5, 128>(h2, qw1, qb1, Q, NN, 256, 1024, 1024, stream);
    attn5_kernel<<<NN, 256, 0, stream>>>(Q, off, csr_src, t1, 256);

    // ---- TransformerConv 2 ----
    launch_gemm<5, 128>(t1, qw2, qb2, Q, NN, 256, 1024, 1024, stream);
    attn5_kernel<<<NN, 256, 0, stream>>>(Q, off, csr_src, h4, 256);

    // ---- proj MLP (p2 fuses sigmoid + grouped max pool) ----
    launch_gemm<2, 128>(h4, p1t, p1_b, p1o, NN, 256, 512, 512, stream);
    launch_gemm<4, 64>(p1o, p2t, p2_b, nullptr, NN, 512, 128, 128, stream, batch, out);
}